// Round 18
// baseline (118.734 us; speedup 1.0000x reference)
//
#include <hip/hip_runtime.h>
#include <hip/hip_bf16.h>

#define B_ 2
#define T_ 2048
#define C_ 1024
#define H_ 16
#define D_ 64
#define M1 4096
#define N1 3072
#define K_ 1024

typedef __attribute__((ext_vector_type(8))) __bf16 bf16x8;
typedef __attribute__((ext_vector_type(4))) float f32x4;
typedef __attribute__((ext_vector_type(8))) unsigned short ushort8_t;
typedef __attribute__((ext_vector_type(4))) unsigned short ushort4_t;
typedef __attribute__((ext_vector_type(2))) unsigned int uint2_t;

static __device__ __forceinline__ unsigned short f2bf(float f) {
    unsigned int u = __builtin_bit_cast(unsigned int, f);
    u += 0x7fffu + ((u >> 16) & 1u);
    return (unsigned short)(u >> 16);
}
static __device__ __forceinline__ unsigned short f2bf_hw(float f) {
    return __builtin_bit_cast(unsigned short, (__bf16)f);
}
static __device__ __forceinline__ unsigned int packbf(float lo, float hi) {
    return (unsigned int)f2bf_hw(lo) | ((unsigned int)f2bf_hw(hi) << 16);
}
static __device__ __forceinline__ bf16x8 bload(const unsigned short* p) {
    return __builtin_bit_cast(bf16x8, *(const ushort8_t*)p);
}

// fast exp2 -> v_exp_f32
#if defined(__has_builtin)
#if __has_builtin(__builtin_amdgcn_exp2f)
#define HAVE_EXP2_BUILTIN 1
#endif
#endif
static __device__ __forceinline__ float fexp2(float x) {
#ifdef HAVE_EXP2_BUILTIN
    return __builtin_amdgcn_exp2f(x);
#else
    float r; asm("v_exp_f32 %0, %1" : "=v"(r) : "v"(x)); return r;
#endif
}

// ---- async global->LDS (16B per lane; LDS dest wave-uniform base + lane*16) ----
typedef __attribute__((address_space(1))) const unsigned int gu32;
typedef __attribute__((address_space(3))) unsigned int lu32;
static __device__ __forceinline__ void gld16(const void* g, void* l) {
    __builtin_amdgcn_global_load_lds((gu32*)g, (lu32*)l, 16, 0, 0);
}

#define VMCNT(n) asm volatile("s_waitcnt vmcnt(" #n ")" ::: "memory")
#define LGKM0    asm volatile("s_waitcnt lgkmcnt(0)" ::: "memory")

// ---------------- cast x -> bf16 ----------------
__global__ void cast_x_kernel(const float* __restrict__ in,
                              unsigned short* __restrict__ out, int n4) {
    int idx = blockIdx.x * blockDim.x + threadIdx.x;
    int stride = gridDim.x * blockDim.x;
    for (int i = idx; i < n4; i += stride) {
        float4 v = ((const float4*)in)[i];
        ushort4_t o;
        o.x = f2bf(v.x); o.y = f2bf(v.y); o.z = f2bf(v.z); o.w = f2bf(v.w);
        ((ushort4_t*)out)[i] = o;
    }
}

// ------------- transpose f32[K][N] -> bf16[N][K] -------------
__global__ void transpose_cast_kernel(const float* __restrict__ in,
                                      unsigned short* __restrict__ out,
                                      int K, int N) {
    __shared__ float tile[32][33];
    int tx = threadIdx.x & 31;
    int ty = threadIdx.x >> 5;
    int n0 = blockIdx.x * 32;
    int k0 = blockIdx.y * 32;
#pragma unroll
    for (int rr = 0; rr < 32; rr += 8)
        tile[ty + rr][tx] = in[(size_t)(k0 + ty + rr) * N + n0 + tx];
    __syncthreads();
#pragma unroll
    for (int rr = 0; rr < 32; rr += 8)
        out[(size_t)(n0 + ty + rr) * K + k0 + tx] = f2bf(tile[tx][ty + rr]);
}

// ======== GEMM K-loop, 512 threads / 8 waves (wave grid 4x2, 32x64/wave) ========
// Granule XOR-swizzle (proven: conflicts 3.1M -> 0): LDS slot s of row r holds
// global granule s ^ ((r>>1)&3); source pre-swizzled, dest linear (rule #21).
// SWAP=false: lane cl owns output COLUMN j; reg r-axis = 4 consecutive rows (t).
// SWAP=true : lane cl owns output ROW    i; reg r-axis = 4 consecutive cols.
template <bool SWAP>
static __device__ __forceinline__ void gemm_loop8(
    const unsigned short* __restrict__ A, const unsigned short* __restrict__ Bt,
    unsigned short (*As)[128 * 32], unsigned short (*Bs)[128 * 32],
    int row0, int col0, int tid, f32x4 (&acc)[2][4])
{
    const int lane = tid & 63;
    const int wave = tid >> 6;             // 0..7
    const int g = lane >> 4, cl = lane & 15;
    const int wr = (wave & 3) * 32, wc = (wave >> 2) * 64;
    const int srow = tid >> 2;             // 0..127
    const int sgran = tid & 3;
#pragma unroll
    for (int m = 0; m < 2; ++m)
#pragma unroll
        for (int n = 0; n < 4; ++n)
            acc[m][n] = (f32x4){0.f, 0.f, 0.f, 0.f};
    const int lg = sgran ^ ((srow >> 1) & 3);
    auto stage = [&](int buf, int k0) {
        gld16(A + (size_t)(row0 + srow) * K_ + k0 + lg * 8,
              (char*)&As[buf][0] + wave * 1024);
        gld16(Bt + (size_t)(col0 + srow) * K_ + k0 + lg * 8,
              (char*)&Bs[buf][0] + wave * 1024);
    };
    stage(0, 0);
    int buf = 0;
    for (int k0 = 0; k0 < K_; k0 += 32) {
        if (k0 + 32 < K_) { stage(buf ^ 1, k0 + 32); VMCNT(2); }
        else              { VMCNT(0); }
        __builtin_amdgcn_s_barrier();
        bf16x8 af[2], bfv[4];
#pragma unroll
        for (int m = 0; m < 2; ++m) {
            int ra = wr + m * 16 + cl;
            af[m] = bload(&As[buf][ra * 32 + (g ^ ((ra >> 1) & 3)) * 8]);
        }
#pragma unroll
        for (int n = 0; n < 4; ++n) {
            int rb = wc + n * 16 + cl;
            bfv[n] = bload(&Bs[buf][rb * 32 + (g ^ ((rb >> 1) & 3)) * 8]);
        }
#pragma unroll
        for (int m = 0; m < 2; ++m)
#pragma unroll
            for (int n = 0; n < 4; ++n)
                acc[m][n] = SWAP
                    ? __builtin_amdgcn_mfma_f32_16x16x32_bf16(bfv[n], af[m], acc[m][n], 0, 0, 0)
                    : __builtin_amdgcn_mfma_f32_16x16x32_bf16(af[m], bfv[n], acc[m][n], 0, 0, 0);
        LGKM0;
        __builtin_amdgcn_s_barrier();
        buf ^= 1;
    }
}

// ---------------- GEMM1: qkv = Xb @ Wt1^T + b (8 waves) ----------------
// XCD-chunked block map: per-XCD 8-row x 12-col region. Unswapped: lane owns
// col j (fixed d); r-axis = 4 consecutive t -> V^T store is one packed 8B write.
__global__ __launch_bounds__(512, 4)
void gemm_qkv_kernel(const unsigned short* __restrict__ A,   // [4096][1024] bf16
                     const unsigned short* __restrict__ Bt,  // [3072][1024] bf16
                     const float* __restrict__ bias,         // [3072]
                     unsigned short* __restrict__ Qo,        // [BH][T][D] (pre-scaled)
                     unsigned short* __restrict__ Ko,        // [BH][T][D]
                     unsigned short* __restrict__ Vt)        // [BH][D][T]
{
    __shared__ unsigned short As[2][128 * 32];
    __shared__ unsigned short Bs[2][128 * 32];
    const int lin = blockIdx.x + gridDim.x * blockIdx.y;  // 0..767
    const int xcd = lin & 7;
    const int idx = lin >> 3;                              // 0..95
    const int bx = (xcd >> 1) * 8 + (idx & 7);             // 0..31
    const int by = (xcd & 1) * 12 + (idx >> 3);            // 0..23
    const int row0 = bx * 128, col0 = by * 128;

    const int tid = threadIdx.x;
    const int lane = tid & 63;
    const int wave = tid >> 6;
    const int g = lane >> 4, cl = lane & 15;
    const int wr = (wave & 3) * 32, wc = (wave >> 2) * 64;

    f32x4 acc[2][4];
    gemm_loop8<false>(A, Bt, As, Bs, row0, col0, tid, acc);

    const float QSCALE = 0.125f * 1.44269504088896340736f;  // 1/sqrt(D) * log2(e)
#pragma unroll
    for (int m = 0; m < 2; ++m) {
        int i0 = row0 + wr + m * 16 + g * 4;
        int b = i0 >> 11, t0 = i0 & 2047;   // 4 consecutive t from t0 (same b)
#pragma unroll
        for (int n = 0; n < 4; ++n) {
            int j = col0 + wc + n * 16 + cl;
            int which = j >> 10;
            int c = j & 1023;
            int h = c >> 6, d = c & 63;
            float bv = bias[j];
            size_t bh = (size_t)(b * H_ + h);
            float v0 = acc[m][n][0] + bv;
            float v1 = acc[m][n][1] + bv;
            float v2 = acc[m][n][2] + bv;
            float v3 = acc[m][n][3] + bv;
            if (which == 2) {
                uint2_t w;
                w.x = packbf(v0, v1);
                w.y = packbf(v2, v3);
                *(uint2_t*)&Vt[(bh * D_ + d) * T_ + t0] = w;
            } else if (which == 0) {
                Qo[(bh * T_ + t0 + 0) * D_ + d] = f2bf_hw(v0 * QSCALE);
                Qo[(bh * T_ + t0 + 1) * D_ + d] = f2bf_hw(v1 * QSCALE);
                Qo[(bh * T_ + t0 + 2) * D_ + d] = f2bf_hw(v2 * QSCALE);
                Qo[(bh * T_ + t0 + 3) * D_ + d] = f2bf_hw(v3 * QSCALE);
            } else {
                Ko[(bh * T_ + t0 + 0) * D_ + d] = f2bf_hw(v0);
                Ko[(bh * T_ + t0 + 1) * D_ + d] = f2bf_hw(v1);
                Ko[(bh * T_ + t0 + 2) * D_ + d] = f2bf_hw(v2);
                Ko[(bh * T_ + t0 + 3) * D_ + d] = f2bf_hw(v3);
            }
        }
    }
}

// -------- GEMM2: out = AO @ Wt2^T + b (fp32 out, swapped -> f32x4 stores, 8 waves) ----
__global__ __launch_bounds__(512, 4)
void gemm_proj_kernel(const unsigned short* __restrict__ A,   // [4096][1024] bf16
                      const unsigned short* __restrict__ Bt,  // [1024][1024] bf16
                      const float* __restrict__ bias,         // [1024]
                      float* __restrict__ out)                // [4096][1024] f32
{
    __shared__ unsigned short As[2][128 * 32];
    __shared__ unsigned short Bs[2][128 * 32];
    const int row0 = blockIdx.x * 128, col0 = blockIdx.y * 128;
    const int tid = threadIdx.x;
    const int lane = tid & 63;
    const int wave = tid >> 6;
    const int g = lane >> 4, cl = lane & 15;
    const int wr = (wave & 3) * 32, wc = (wave >> 2) * 64;

    f32x4 acc[2][4];
    gemm_loop8<true>(A, Bt, As, Bs, row0, col0, tid, acc);

#pragma unroll
    for (int m = 0; m < 2; ++m) {
        int i = row0 + wr + m * 16 + cl;
#pragma unroll
        for (int n = 0; n < 4; ++n) {
            int j0 = col0 + wc + n * 16 + g * 4;
            float4 bv = *(const float4*)&bias[j0];
            f32x4 o = acc[m][n];
            o[0] += bv.x; o[1] += bv.y; o[2] += bv.z; o[3] += bv.w;
            *(f32x4*)&out[(size_t)i * C_ + j0] = o;
        }
    }
}

// ---------------- flash attention (R12 body, CU-sum-balanced mapping) ----------------
// grid 1024, 4 resident blocks/CU (no backfill) -> wall = worst CU's step total.
// Blocks i, i+32, i+64, i+96 (xcd-local, same CU under round-robin) get qt values
// with nk summing exactly 66 for EVERY CU: slot j=i>>5, c=i&31;
//   cc = (j&2) ? (c+16)&31 : c;  qt = (j&1) ? 31-cc : cc;  bh = xcd + 8*j.
// Each j-slot's qt is a permutation of 0..31 -> bijective; 4 heads/XCD kept.
// Swapped operands: lane owns q-row. Lane-local online softmax + defer-max THR=8.
__global__ __launch_bounds__(256)
void attn_kernel(const unsigned short* __restrict__ Q,   // [BH][T][D], pre-scaled
                 const unsigned short* __restrict__ Kb,  // [BH][T][D]
                 const unsigned short* __restrict__ Vh_, // [BH][D][T]
                 unsigned short* __restrict__ AO)        // [B][T][C] bf16
{
    __shared__ unsigned short Klds[2][64 * 64];   // 16 KB
    __shared__ unsigned short Vlds[2][64 * 64];   // 16 KB
    __shared__ unsigned short Plds[4][16 * 64];   // 8 KB, XOR-swizzled rows
    const int lin = blockIdx.x;                   // 0..1023
    const int xcd = lin & 7;
    const int i = lin >> 3;                       // 0..127 (xcd-local)
    const int c = i & 31;
    const int j = i >> 5;                         // 0..3 (resident slot)
    const int bh = xcd + 8 * j;                   // 4 heads/XCD (L2-pinned)
    const int cc = (j & 2) ? ((c + 16) & 31) : c;
    const int qt = (j & 1) ? (31 - cc) : cc;
    const int b = bh >> 4, h = bh & 15;
    const int tid = threadIdx.x;
    const int lane = tid & 63;
    const int wave = tid >> 6;
    const int g = lane >> 4, cl = lane & 15;

    const unsigned short* Qh = Q + (size_t)bh * T_ * D_;
    const unsigned short* Kh = Kb + (size_t)bh * T_ * D_;
    const unsigned short* Vh = Vh_ + (size_t)bh * D_ * T_;

    const int srow = tid >> 3;  // 0..31
    const int sg   = tid & 7;
    const int pswz = (cl & 7) << 4;   // Plds byte-XOR (same involution write & read)

    auto stage = [&](int bufi, int kb) {
#pragma unroll
        for (int cc2 = 0; cc2 < 2; ++cc2) {
            int r = srow + cc2 * 32;
            int lg = sg ^ (r & 7);
            gld16(Kh + (size_t)(kb + r) * D_ + lg * 8,
                  (char*)&Klds[bufi][0] + cc2 * 4096 + wave * 1024);
            gld16(Vh + (size_t)r * T_ + kb + lg * 8,
                  (char*)&Vlds[bufi][0] + cc2 * 4096 + wave * 1024);
        }
    };

    const int q0 = qt * 64 + wave * 16;
    const int tq = q0 + cl;   // this lane's q row

    bf16x8 qf[2];
#pragma unroll
    for (int c2 = 0; c2 < 2; ++c2)
        qf[c2] = bload(Qh + (size_t)(q0 + cl) * D_ + c2 * 32 + g * 8);

    f32x4 oacc[4];
#pragma unroll
    for (int n = 0; n < 4; ++n) oacc[n] = (f32x4){0.f, 0.f, 0.f, 0.f};
    float m_run = -INFINITY;   // row-consistent (only updated under reduction)
    float l_part = 0.f;        // LANE-LOCAL partial; reduced at epilogue

    const int nk = qt + 1;
    stage(0, 0);
    int buf = 0;
    for (int kt = 0; kt < nk; ++kt) {
        if (kt + 1 < nk) { stage(buf ^ 1, (kt + 1) * 64); VMCNT(4); }
        else             { VMCNT(0); }
        __builtin_amdgcn_s_barrier();

        const int kb = kt * 64;
        // ---- QK^T (swapped): sc[n] row = k, col = q ----
        f32x4 sc[4];
        __builtin_amdgcn_s_setprio(1);
#pragma unroll
        for (int n = 0; n < 4; ++n) {
            sc[n] = (f32x4){0.f, 0.f, 0.f, 0.f};
#pragma unroll
            for (int c2 = 0; c2 < 2; ++c2) {
                int pg = (c2 * 4 + g) ^ (cl & 7);
                bf16x8 kf = bload(&Klds[buf][(n * 16 + cl) * 64 + pg * 8]);
                sc[n] = __builtin_amdgcn_mfma_f32_16x16x32_bf16(kf, qf[c2], sc[n], 0, 0, 0);
            }
        }
        __builtin_amdgcn_s_setprio(0);
        // ---- causal mask (diagonal tile only); k = kb + n*16 + g*4 + r ----
        if (kt == qt) {
#pragma unroll
            for (int n = 0; n < 4; ++n) {
                int k4 = kb + n * 16 + g * 4;
#pragma unroll
                for (int r = 0; r < 4; ++r)
                    if (k4 + r > tq) sc[n][r] = -INFINITY;
            }
        }
        // ---- lane-local online softmax (defer-max THR=8, cross-lane only on rescale) ----
        float mx[4];
#pragma unroll
        for (int n = 0; n < 4; ++n)
            mx[n] = fmaxf(fmaxf(sc[n][0], sc[n][1]), fmaxf(sc[n][2], sc[n][3]));
        float lm = fmaxf(fmaxf(mx[0], mx[1]), fmaxf(mx[2], mx[3]));
        if (!__all(lm <= m_run + 8.f)) {
            float vmax = lm;
            vmax = fmaxf(vmax, __shfl_xor(vmax, 16, 64));
            vmax = fmaxf(vmax, __shfl_xor(vmax, 32, 64));
            float mn = fmaxf(m_run, vmax);
            float alpha = fexp2(m_run - mn);
            l_part *= alpha;
#pragma unroll
            for (int n = 0; n < 4; ++n)
#pragma unroll
                for (int r = 0; r < 4; ++r) oacc[n][r] *= alpha;
            m_run = mn;
        }
        float p[4][4], psub[4];
#pragma unroll
        for (int n = 0; n < 4; ++n) {
#pragma unroll
            for (int r = 0; r < 4; ++r) p[n][r] = fexp2(sc[n][r] - m_run);
            psub[n] = (p[n][0] + p[n][1]) + (p[n][2] + p[n][3]);
        }
        l_part += (psub[0] + psub[1]) + (psub[2] + psub[3]);
        // ---- P: pack bf16 pairs, 4x ds_write_b64 into own (swizzled) q-row ----
#pragma unroll
        for (int n = 0; n < 4; ++n) {
            uint2_t w;
            w.x = packbf(p[n][0], p[n][1]);
            w.y = packbf(p[n][2], p[n][3]);
            *(uint2_t*)((char*)&Plds[wave][0] + ((cl * 128 + n * 32 + g * 8) ^ pswz)) = w;
        }
        bf16x8 pf[2];
#pragma unroll
        for (int kk = 0; kk < 2; ++kk)
            pf[kk] = bload((const unsigned short*)
                ((char*)&Plds[wave][0] + ((cl * 128 + kk * 64 + g * 16) ^ pswz)));
        // ---- PV (swapped): O^T += mfma(V^T-frag, P^T-frag) ----
        __builtin_amdgcn_s_setprio(1);
#pragma unroll
        for (int n = 0; n < 4; ++n) {
#pragma unroll
            for (int kk = 0; kk < 2; ++kk) {
                int pg = (kk * 4 + g) ^ (cl & 7);
                bf16x8 vfr = bload(&Vlds[buf][(n * 16 + cl) * 64 + pg * 8]);
                oacc[n] = __builtin_amdgcn_mfma_f32_16x16x32_bf16(vfr, pf[kk], oacc[n], 0, 0, 0);
            }
        }
        __builtin_amdgcn_s_setprio(0);
        LGKM0;
        __builtin_amdgcn_s_barrier();
        buf ^= 1;
    }
    // ---- epilogue: reduce l across the 4 g-lanes of the row, then store ----
    float lt = l_part;
    lt += __shfl_xor(lt, 16, 64);
    lt += __shfl_xor(lt, 32, 64);
    float inv = 1.f / lt;
#pragma unroll
    for (int n = 0; n < 4; ++n) {
        uint2_t w;
        w.x = packbf(oacc[n][0] * inv, oacc[n][1] * inv);
        w.y = packbf(oacc[n][2] * inv, oacc[n][3] * inv);
        *(uint2_t*)&AO[((size_t)b * T_ + tq) * C_ + h * D_ + n * 16 + g * 4] = w;
    }
}

extern "C" void kernel_launch(void* const* d_in, const int* in_sizes, int n_in,
                              void* d_out, int out_size, void* d_ws, size_t ws_size,
                              hipStream_t stream) {
    (void)in_sizes; (void)n_in; (void)out_size; (void)ws_size;
    const float* x      = (const float*)d_in[0];
    const float* w_attn = (const float*)d_in[1];
    const float* b_attn = (const float*)d_in[2];
    const float* w_proj = (const float*)d_in[3];
    const float* b_proj = (const float*)d_in[4];
    float* out = (float*)d_out;

    char* ws = (char*)d_ws;
    unsigned short* Xb  = (unsigned short*)(ws);
    unsigned short* Wt1 = (unsigned short*)(ws + ((size_t)8  << 20));
    unsigned short* Wt2 = (unsigned short*)(ws + ((size_t)14 << 20));
    unsigned short* Qb  = (unsigned short*)(ws + ((size_t)16 << 20));
    unsigned short* Kb  = (unsigned short*)(ws + ((size_t)24 << 20));
    unsigned short* Vt  = (unsigned short*)(ws + ((size_t)32 << 20));
    unsigned short* AO  = Xb;  // Xb dead after gemm_qkv

    cast_x_kernel<<<1024, 256, 0, stream>>>(x, Xb, (M1 * K_) / 4);
    transpose_cast_kernel<<<dim3(N1 / 32, K_ / 32), 256, 0, stream>>>(w_attn, Wt1, K_, N1);
    transpose_cast_kernel<<<dim3(C_ / 32, K_ / 32), 256, 0, stream>>>(w_proj, Wt2, K_, C_);
    gemm_qkv_kernel<<<dim3(M1 / 128, N1 / 128), 512, 0, stream>>>(Xb, Wt1, b_attn, Qb, Kb, Vt);
    attn_kernel<<<1024, 256, 0, stream>>>(Qb, Kb, Vt, AO);
    gemm_proj_kernel<<<dim3(M1 / 128, C_ / 128), 512, 0, stream>>>(AO, Wt2, b_proj, out);
}

// Round 19
// 109.976 us; speedup vs baseline: 1.0796x; 1.0796x over previous
//
#include <hip/hip_runtime.h>
#include <hip/hip_bf16.h>

#define B_ 2
#define T_ 2048
#define C_ 1024
#define H_ 16
#define D_ 64
#define M1 4096
#define N1 3072
#define K_ 1024

typedef __attribute__((ext_vector_type(8))) __bf16 bf16x8;
typedef __attribute__((ext_vector_type(4))) float f32x4;
typedef __attribute__((ext_vector_type(8))) unsigned short ushort8_t;
typedef __attribute__((ext_vector_type(4))) unsigned short ushort4_t;
typedef __attribute__((ext_vector_type(2))) unsigned int uint2_t;

static __device__ __forceinline__ unsigned short f2bf(float f) {
    unsigned int u = __builtin_bit_cast(unsigned int, f);
    u += 0x7fffu + ((u >> 16) & 1u);
    return (unsigned short)(u >> 16);
}
static __device__ __forceinline__ unsigned short f2bf_hw(float f) {
    return __builtin_bit_cast(unsigned short, (__bf16)f);
}
static __device__ __forceinline__ unsigned int packbf(float lo, float hi) {
    return (unsigned int)f2bf_hw(lo) | ((unsigned int)f2bf_hw(hi) << 16);
}
static __device__ __forceinline__ bf16x8 bload(const unsigned short* p) {
    return __builtin_bit_cast(bf16x8, *(const ushort8_t*)p);
}

// fast exp2 -> v_exp_f32
#if defined(__has_builtin)
#if __has_builtin(__builtin_amdgcn_exp2f)
#define HAVE_EXP2_BUILTIN 1
#endif
#endif
static __device__ __forceinline__ float fexp2(float x) {
#ifdef HAVE_EXP2_BUILTIN
    return __builtin_amdgcn_exp2f(x);
#else
    float r; asm("v_exp_f32 %0, %1" : "=v"(r) : "v"(x)); return r;
#endif
}

// ---- async global->LDS (16B per lane; LDS dest wave-uniform base + lane*16) ----
typedef __attribute__((address_space(1))) const unsigned int gu32;
typedef __attribute__((address_space(3))) unsigned int lu32;
static __device__ __forceinline__ void gld16(const void* g, void* l) {
    __builtin_amdgcn_global_load_lds((gu32*)g, (lu32*)l, 16, 0, 0);
}

#define VMCNT(n) asm volatile("s_waitcnt vmcnt(" #n ")" ::: "memory")
#define LGKM0    asm volatile("s_waitcnt lgkmcnt(0)" ::: "memory")

// ============ fused prologue: cast x + transpose both weights ============
// blocks [0,1024): x -> bf16 (grid-stride over 1M float4)
// blocks [1024,4096): w_attn f32[1024][3072] -> bf16 Wt1[3072][1024]
// blocks [4096,5120): w_proj f32[1024][1024] -> bf16 Wt2[1024][1024]
__global__ __launch_bounds__(256)
void prologue_kernel(const float* __restrict__ x,
                     const float* __restrict__ w_attn,
                     const float* __restrict__ w_proj,
                     unsigned short* __restrict__ Xb,
                     unsigned short* __restrict__ Wt1,
                     unsigned short* __restrict__ Wt2)
{
    __shared__ float tile[32][33];
    const int blk = blockIdx.x;
    if (blk < 1024) {
        int idx = blk * 256 + threadIdx.x;
        const int n4 = (M1 * K_) / 4;
        for (int i = idx; i < n4; i += 1024 * 256) {
            float4 v = ((const float4*)x)[i];
            ushort4_t o;
            o.x = f2bf(v.x); o.y = f2bf(v.y); o.z = f2bf(v.z); o.w = f2bf(v.w);
            ((ushort4_t*)Xb)[i] = o;
        }
        return;
    }
    const float* in;
    unsigned short* out;
    int N, bx, by;
    if (blk < 4096) {
        in = w_attn; out = Wt1; N = N1;
        int t = blk - 1024;            // 0..3071 : (N1/32=96) x (K/32=32)
        bx = t % 96; by = t / 96;
    } else {
        in = w_proj; out = Wt2; N = C_;
        int t = blk - 4096;            // 0..1023 : 32 x 32
        bx = t % 32; by = t / 32;
    }
    int tx = threadIdx.x & 31;
    int ty = threadIdx.x >> 5;
    int n0 = bx * 32;
    int k0 = by * 32;
#pragma unroll
    for (int rr = 0; rr < 32; rr += 8)
        tile[ty + rr][tx] = in[(size_t)(k0 + ty + rr) * N + n0 + tx];
    __syncthreads();
#pragma unroll
    for (int rr = 0; rr < 32; rr += 8)
        out[(size_t)(n0 + ty + rr) * K_ + k0 + tx] = f2bf(tile[tx][ty + rr]);
}

// ======== GEMM K-loop, 512 threads / 8 waves (wave grid 4x2, 32x64/wave) ========
// Granule XOR-swizzle (proven: conflicts 3.1M -> 0): LDS slot s of row r holds
// global granule s ^ ((r>>1)&3); source pre-swizzled, dest linear (rule #21).
// SWAP=false: lane cl owns output COLUMN j; reg r-axis = 4 consecutive rows (t).
// SWAP=true : lane cl owns output ROW    i; reg r-axis = 4 consecutive cols.
template <bool SWAP>
static __device__ __forceinline__ void gemm_loop8(
    const unsigned short* __restrict__ A, const unsigned short* __restrict__ Bt,
    unsigned short (*As)[128 * 32], unsigned short (*Bs)[128 * 32],
    int row0, int col0, int tid, f32x4 (&acc)[2][4])
{
    const int lane = tid & 63;
    const int wave = tid >> 6;             // 0..7
    const int g = lane >> 4, cl = lane & 15;
    const int wr = (wave & 3) * 32, wc = (wave >> 2) * 64;
    const int srow = tid >> 2;             // 0..127
    const int sgran = tid & 3;
#pragma unroll
    for (int m = 0; m < 2; ++m)
#pragma unroll
        for (int n = 0; n < 4; ++n)
            acc[m][n] = (f32x4){0.f, 0.f, 0.f, 0.f};
    const int lg = sgran ^ ((srow >> 1) & 3);
    auto stage = [&](int buf, int k0) {
        gld16(A + (size_t)(row0 + srow) * K_ + k0 + lg * 8,
              (char*)&As[buf][0] + wave * 1024);
        gld16(Bt + (size_t)(col0 + srow) * K_ + k0 + lg * 8,
              (char*)&Bs[buf][0] + wave * 1024);
    };
    stage(0, 0);
    int buf = 0;
    for (int k0 = 0; k0 < K_; k0 += 32) {
        if (k0 + 32 < K_) { stage(buf ^ 1, k0 + 32); VMCNT(2); }
        else              { VMCNT(0); }
        __builtin_amdgcn_s_barrier();
        bf16x8 af[2], bfv[4];
#pragma unroll
        for (int m = 0; m < 2; ++m) {
            int ra = wr + m * 16 + cl;
            af[m] = bload(&As[buf][ra * 32 + (g ^ ((ra >> 1) & 3)) * 8]);
        }
#pragma unroll
        for (int n = 0; n < 4; ++n) {
            int rb = wc + n * 16 + cl;
            bfv[n] = bload(&Bs[buf][rb * 32 + (g ^ ((rb >> 1) & 3)) * 8]);
        }
#pragma unroll
        for (int m = 0; m < 2; ++m)
#pragma unroll
            for (int n = 0; n < 4; ++n)
                acc[m][n] = SWAP
                    ? __builtin_amdgcn_mfma_f32_16x16x32_bf16(bfv[n], af[m], acc[m][n], 0, 0, 0)
                    : __builtin_amdgcn_mfma_f32_16x16x32_bf16(af[m], bfv[n], acc[m][n], 0, 0, 0);
        LGKM0;
        __builtin_amdgcn_s_barrier();
        buf ^= 1;
    }
}

// ---------------- GEMM1: qkv = Xb @ Wt1^T + b (8 waves) ----------------
// XCD-chunked block map: per-XCD 8-row x 12-col region. Unswapped: lane owns
// col j (fixed d); r-axis = 4 consecutive t -> V^T store is one packed 8B write.
__global__ __launch_bounds__(512, 4)
void gemm_qkv_kernel(const unsigned short* __restrict__ A,   // [4096][1024] bf16
                     const unsigned short* __restrict__ Bt,  // [3072][1024] bf16
                     const float* __restrict__ bias,         // [3072]
                     unsigned short* __restrict__ Qo,        // [BH][T][D] (pre-scaled)
                     unsigned short* __restrict__ Ko,        // [BH][T][D]
                     unsigned short* __restrict__ Vt)        // [BH][D][T]
{
    __shared__ unsigned short As[2][128 * 32];
    __shared__ unsigned short Bs[2][128 * 32];
    const int lin = blockIdx.x + gridDim.x * blockIdx.y;  // 0..767
    const int xcd = lin & 7;
    const int idx = lin >> 3;                              // 0..95
    const int bx = (xcd >> 1) * 8 + (idx & 7);             // 0..31
    const int by = (xcd & 1) * 12 + (idx >> 3);            // 0..23
    const int row0 = bx * 128, col0 = by * 128;

    const int tid = threadIdx.x;
    const int lane = tid & 63;
    const int wave = tid >> 6;
    const int g = lane >> 4, cl = lane & 15;
    const int wr = (wave & 3) * 32, wc = (wave >> 2) * 64;

    f32x4 acc[2][4];
    gemm_loop8<false>(A, Bt, As, Bs, row0, col0, tid, acc);

    const float QSCALE = 0.125f * 1.44269504088896340736f;  // 1/sqrt(D) * log2(e)
#pragma unroll
    for (int m = 0; m < 2; ++m) {
        int i0 = row0 + wr + m * 16 + g * 4;
        int b = i0 >> 11, t0 = i0 & 2047;   // 4 consecutive t from t0 (same b)
#pragma unroll
        for (int n = 0; n < 4; ++n) {
            int j = col0 + wc + n * 16 + cl;
            int which = j >> 10;
            int c = j & 1023;
            int h = c >> 6, d = c & 63;
            float bv = bias[j];
            size_t bh = (size_t)(b * H_ + h);
            float v0 = acc[m][n][0] + bv;
            float v1 = acc[m][n][1] + bv;
            float v2 = acc[m][n][2] + bv;
            float v3 = acc[m][n][3] + bv;
            if (which == 2) {
                uint2_t w;
                w.x = packbf(v0, v1);
                w.y = packbf(v2, v3);
                *(uint2_t*)&Vt[(bh * D_ + d) * T_ + t0] = w;
            } else if (which == 0) {
                Qo[(bh * T_ + t0 + 0) * D_ + d] = f2bf_hw(v0 * QSCALE);
                Qo[(bh * T_ + t0 + 1) * D_ + d] = f2bf_hw(v1 * QSCALE);
                Qo[(bh * T_ + t0 + 2) * D_ + d] = f2bf_hw(v2 * QSCALE);
                Qo[(bh * T_ + t0 + 3) * D_ + d] = f2bf_hw(v3 * QSCALE);
            } else {
                Ko[(bh * T_ + t0 + 0) * D_ + d] = f2bf_hw(v0);
                Ko[(bh * T_ + t0 + 1) * D_ + d] = f2bf_hw(v1);
                Ko[(bh * T_ + t0 + 2) * D_ + d] = f2bf_hw(v2);
                Ko[(bh * T_ + t0 + 3) * D_ + d] = f2bf_hw(v3);
            }
        }
    }
}

// -------- GEMM2: out = AO @ Wt2^T + b (fp32 out, swapped -> f32x4 stores, 8 waves) ----
__global__ __launch_bounds__(512, 4)
void gemm_proj_kernel(const unsigned short* __restrict__ A,   // [4096][1024] bf16
                      const unsigned short* __restrict__ Bt,  // [1024][1024] bf16
                      const float* __restrict__ bias,         // [1024]
                      float* __restrict__ out)                // [4096][1024] f32
{
    __shared__ unsigned short As[2][128 * 32];
    __shared__ unsigned short Bs[2][128 * 32];
    const int row0 = blockIdx.x * 128, col0 = blockIdx.y * 128;
    const int tid = threadIdx.x;
    const int lane = tid & 63;
    const int wave = tid >> 6;
    const int g = lane >> 4, cl = lane & 15;
    const int wr = (wave & 3) * 32, wc = (wave >> 2) * 64;

    f32x4 acc[2][4];
    gemm_loop8<true>(A, Bt, As, Bs, row0, col0, tid, acc);

#pragma unroll
    for (int m = 0; m < 2; ++m) {
        int i = row0 + wr + m * 16 + cl;
#pragma unroll
        for (int n = 0; n < 4; ++n) {
            int j0 = col0 + wc + n * 16 + g * 4;
            float4 bv = *(const float4*)&bias[j0];
            f32x4 o = acc[m][n];
            o[0] += bv.x; o[1] += bv.y; o[2] += bv.z; o[3] += bv.w;
            *(f32x4*)&out[(size_t)i * C_ + j0] = o;
        }
    }
}

// ---------------- flash attention (R17 verbatim — proven ~49us) ----------------
// grid 1024 (1-D): xcd = lin&7; bh = xcd+8*(idx&3) -> 4 heads/XCD (L2-resident);
// qt = 31-(idx>>2) -> longest tiles dispatch first. LDS 40960 B = 4 blocks/CU.
// Swapped operands: lane owns q-row. Lane-local online softmax + defer-max THR=8.
__global__ __launch_bounds__(256)
void attn_kernel(const unsigned short* __restrict__ Q,   // [BH][T][D], pre-scaled
                 const unsigned short* __restrict__ Kb,  // [BH][T][D]
                 const unsigned short* __restrict__ Vh_, // [BH][D][T]
                 unsigned short* __restrict__ AO)        // [B][T][C] bf16
{
    __shared__ unsigned short Klds[2][64 * 64];   // 16 KB
    __shared__ unsigned short Vlds[2][64 * 64];   // 16 KB
    __shared__ unsigned short Plds[4][16 * 64];   // 8 KB, XOR-swizzled rows
    const int lin = blockIdx.x;                   // 0..1023
    const int idx = lin >> 3;                     // 0..127
    const int bh  = (lin & 7) + 8 * (idx & 3);    // 0..31, head pinned to one XCD
    const int qt  = 31 - (idx >> 2);              // long tiles first
    const int b = bh >> 4, h = bh & 15;
    const int tid = threadIdx.x;
    const int lane = tid & 63;
    const int wave = tid >> 6;
    const int g = lane >> 4, cl = lane & 15;

    const unsigned short* Qh = Q + (size_t)bh * T_ * D_;
    const unsigned short* Kh = Kb + (size_t)bh * T_ * D_;
    const unsigned short* Vh = Vh_ + (size_t)bh * D_ * T_;

    const int srow = tid >> 3;  // 0..31
    const int sg   = tid & 7;
    const int pswz = (cl & 7) << 4;   // Plds byte-XOR (same involution write & read)

    auto stage = [&](int bufi, int kb) {
#pragma unroll
        for (int c = 0; c < 2; ++c) {
            int r = srow + c * 32;
            int lg = sg ^ (r & 7);
            gld16(Kh + (size_t)(kb + r) * D_ + lg * 8,
                  (char*)&Klds[bufi][0] + c * 4096 + wave * 1024);
            gld16(Vh + (size_t)r * T_ + kb + lg * 8,
                  (char*)&Vlds[bufi][0] + c * 4096 + wave * 1024);
        }
    };

    const int q0 = qt * 64 + wave * 16;
    const int tq = q0 + cl;   // this lane's q row

    bf16x8 qf[2];
#pragma unroll
    for (int c2 = 0; c2 < 2; ++c2)
        qf[c2] = bload(Qh + (size_t)(q0 + cl) * D_ + c2 * 32 + g * 8);

    f32x4 oacc[4];
#pragma unroll
    for (int n = 0; n < 4; ++n) oacc[n] = (f32x4){0.f, 0.f, 0.f, 0.f};
    float m_run = -INFINITY;   // row-consistent (only updated under reduction)
    float l_part = 0.f;        // LANE-LOCAL partial; reduced at epilogue

    const int nk = qt + 1;
    stage(0, 0);
    int buf = 0;
    for (int kt = 0; kt < nk; ++kt) {
        if (kt + 1 < nk) { stage(buf ^ 1, (kt + 1) * 64); VMCNT(4); }
        else             { VMCNT(0); }
        __builtin_amdgcn_s_barrier();

        const int kb = kt * 64;
        // ---- QK^T (swapped): sc[n] row = k, col = q ----
        f32x4 sc[4];
        __builtin_amdgcn_s_setprio(1);
#pragma unroll
        for (int n = 0; n < 4; ++n) {
            sc[n] = (f32x4){0.f, 0.f, 0.f, 0.f};
#pragma unroll
            for (int c2 = 0; c2 < 2; ++c2) {
                int pg = (c2 * 4 + g) ^ (cl & 7);
                bf16x8 kf = bload(&Klds[buf][(n * 16 + cl) * 64 + pg * 8]);
                sc[n] = __builtin_amdgcn_mfma_f32_16x16x32_bf16(kf, qf[c2], sc[n], 0, 0, 0);
            }
        }
        __builtin_amdgcn_s_setprio(0);
        // ---- causal mask (diagonal tile only); k = kb + n*16 + g*4 + r ----
        if (kt == qt) {
#pragma unroll
            for (int n = 0; n < 4; ++n) {
                int k4 = kb + n * 16 + g * 4;
#pragma unroll
                for (int r = 0; r < 4; ++r)
                    if (k4 + r > tq) sc[n][r] = -INFINITY;
            }
        }
        // ---- lane-local online softmax (defer-max THR=8, cross-lane only on rescale) ----
        float mx[4];
#pragma unroll
        for (int n = 0; n < 4; ++n)
            mx[n] = fmaxf(fmaxf(sc[n][0], sc[n][1]), fmaxf(sc[n][2], sc[n][3]));
        float lm = fmaxf(fmaxf(mx[0], mx[1]), fmaxf(mx[2], mx[3]));
        if (!__all(lm <= m_run + 8.f)) {
            float vmax = lm;
            vmax = fmaxf(vmax, __shfl_xor(vmax, 16, 64));
            vmax = fmaxf(vmax, __shfl_xor(vmax, 32, 64));
            float mn = fmaxf(m_run, vmax);
            float alpha = fexp2(m_run - mn);
            l_part *= alpha;
#pragma unroll
            for (int n = 0; n < 4; ++n)
#pragma unroll
                for (int r = 0; r < 4; ++r) oacc[n][r] *= alpha;
            m_run = mn;
        }
        float p[4][4], psub[4];
#pragma unroll
        for (int n = 0; n < 4; ++n) {
#pragma unroll
            for (int r = 0; r < 4; ++r) p[n][r] = fexp2(sc[n][r] - m_run);
            psub[n] = (p[n][0] + p[n][1]) + (p[n][2] + p[n][3]);
        }
        l_part += (psub[0] + psub[1]) + (psub[2] + psub[3]);
        // ---- P: pack bf16 pairs, 4x ds_write_b64 into own (swizzled) q-row ----
#pragma unroll
        for (int n = 0; n < 4; ++n) {
            uint2_t w;
            w.x = packbf(p[n][0], p[n][1]);
            w.y = packbf(p[n][2], p[n][3]);
            *(uint2_t*)((char*)&Plds[wave][0] + ((cl * 128 + n * 32 + g * 8) ^ pswz)) = w;
        }
        bf16x8 pf[2];
#pragma unroll
        for (int kk = 0; kk < 2; ++kk)
            pf[kk] = bload((const unsigned short*)
                ((char*)&Plds[wave][0] + ((cl * 128 + kk * 64 + g * 16) ^ pswz)));
        // ---- PV (swapped): O^T += mfma(V^T-frag, P^T-frag) ----
        __builtin_amdgcn_s_setprio(1);
#pragma unroll
        for (int n = 0; n < 4; ++n) {
#pragma unroll
            for (int kk = 0; kk < 2; ++kk) {
                int pg = (kk * 4 + g) ^ (cl & 7);
                bf16x8 vfr = bload(&Vlds[buf][(n * 16 + cl) * 64 + pg * 8]);
                oacc[n] = __builtin_amdgcn_mfma_f32_16x16x32_bf16(vfr, pf[kk], oacc[n], 0, 0, 0);
            }
        }
        __builtin_amdgcn_s_setprio(0);
        LGKM0;
        __builtin_amdgcn_s_barrier();
        buf ^= 1;
    }
    // ---- epilogue: reduce l across the 4 g-lanes of the row, then store ----
    float lt = l_part;
    lt += __shfl_xor(lt, 16, 64);
    lt += __shfl_xor(lt, 32, 64);
    float inv = 1.f / lt;
#pragma unroll
    for (int n = 0; n < 4; ++n) {
        uint2_t w;
        w.x = packbf(oacc[n][0] * inv, oacc[n][1] * inv);
        w.y = packbf(oacc[n][2] * inv, oacc[n][3] * inv);
        *(uint2_t*)&AO[((size_t)b * T_ + tq) * C_ + h * D_ + n * 16 + g * 4] = w;
    }
}

extern "C" void kernel_launch(void* const* d_in, const int* in_sizes, int n_in,
                              void* d_out, int out_size, void* d_ws, size_t ws_size,
                              hipStream_t stream) {
    (void)in_sizes; (void)n_in; (void)out_size; (void)ws_size;
    const float* x      = (const float*)d_in[0];
    const float* w_attn = (const float*)d_in[1];
    const float* b_attn = (const float*)d_in[2];
    const float* w_proj = (const float*)d_in[3];
    const float* b_proj = (const float*)d_in[4];
    float* out = (float*)d_out;

    char* ws = (char*)d_ws;
    unsigned short* Xb  = (unsigned short*)(ws);
    unsigned short* Wt1 = (unsigned short*)(ws + ((size_t)8  << 20));
    unsigned short* Wt2 = (unsigned short*)(ws + ((size_t)14 << 20));
    unsigned short* Qb  = (unsigned short*)(ws + ((size_t)16 << 20));
    unsigned short* Kb  = (unsigned short*)(ws + ((size_t)24 << 20));
    unsigned short* Vt  = (unsigned short*)(ws + ((size_t)32 << 20));
    unsigned short* AO  = Xb;  // Xb dead after gemm_qkv

    prologue_kernel<<<5120, 256, 0, stream>>>(x, w_attn, w_proj, Xb, Wt1, Wt2);
    gemm_qkv_kernel<<<dim3(M1 / 128, N1 / 128), 512, 0, stream>>>(Xb, Wt1, b_attn, Qb, Kb, Vt);
    attn_kernel<<<1024, 256, 0, stream>>>(Qb, Kb, Vt, AO);
    gemm_proj_kernel<<<dim3(M1 / 128, C_ / 128), 512, 0, stream>>>(AO, Wt2, b_proj, out);
}

// Round 20
// 106.533 us; speedup vs baseline: 1.1145x; 1.0323x over previous
//
#include <hip/hip_runtime.h>
#include <hip/hip_bf16.h>

#define B_ 2
#define T_ 2048
#define C_ 1024
#define H_ 16
#define D_ 64
#define M1 4096
#define N1 3072
#define K_ 1024

typedef __attribute__((ext_vector_type(8))) __bf16 bf16x8;
typedef __attribute__((ext_vector_type(4))) float f32x4;
typedef __attribute__((ext_vector_type(8))) unsigned short ushort8_t;
typedef __attribute__((ext_vector_type(4))) unsigned short ushort4_t;
typedef __attribute__((ext_vector_type(2))) unsigned int uint2_t;

static __device__ __forceinline__ unsigned short f2bf(float f) {
    unsigned int u = __builtin_bit_cast(unsigned int, f);
    u += 0x7fffu + ((u >> 16) & 1u);
    return (unsigned short)(u >> 16);
}
static __device__ __forceinline__ unsigned short f2bf_hw(float f) {
    return __builtin_bit_cast(unsigned short, (__bf16)f);
}
static __device__ __forceinline__ unsigned int packbf(float lo, float hi) {
    return (unsigned int)f2bf_hw(lo) | ((unsigned int)f2bf_hw(hi) << 16);
}
static __device__ __forceinline__ bf16x8 bload(const unsigned short* p) {
    return __builtin_bit_cast(bf16x8, *(const ushort8_t*)p);
}

// fast exp2 -> v_exp_f32
#if defined(__has_builtin)
#if __has_builtin(__builtin_amdgcn_exp2f)
#define HAVE_EXP2_BUILTIN 1
#endif
#endif
static __device__ __forceinline__ float fexp2(float x) {
#ifdef HAVE_EXP2_BUILTIN
    return __builtin_amdgcn_exp2f(x);
#else
    float r; asm("v_exp_f32 %0, %1" : "=v"(r) : "v"(x)); return r;
#endif
}

// ---- async global->LDS (16B per lane; LDS dest wave-uniform base + lane*16) ----
typedef __attribute__((address_space(1))) const unsigned int gu32;
typedef __attribute__((address_space(3))) unsigned int lu32;
static __device__ __forceinline__ void gld16(const void* g, void* l) {
    __builtin_amdgcn_global_load_lds((gu32*)g, (lu32*)l, 16, 0, 0);
}

#define VMCNT(n) asm volatile("s_waitcnt vmcnt(" #n ")" ::: "memory")
#define LGKM0    asm volatile("s_waitcnt lgkmcnt(0)" ::: "memory")

// ============ fused prologue: cast x + transpose both weights ============
__global__ __launch_bounds__(256)
void prologue_kernel(const float* __restrict__ x,
                     const float* __restrict__ w_attn,
                     const float* __restrict__ w_proj,
                     unsigned short* __restrict__ Xb,
                     unsigned short* __restrict__ Wt1,
                     unsigned short* __restrict__ Wt2)
{
    __shared__ float tile[32][33];
    const int blk = blockIdx.x;
    if (blk < 1024) {
        int idx = blk * 256 + threadIdx.x;
        const int n4 = (M1 * K_) / 4;
        for (int i = idx; i < n4; i += 1024 * 256) {
            float4 v = ((const float4*)x)[i];
            ushort4_t o;
            o.x = f2bf(v.x); o.y = f2bf(v.y); o.z = f2bf(v.z); o.w = f2bf(v.w);
            ((ushort4_t*)Xb)[i] = o;
        }
        return;
    }
    const float* in;
    unsigned short* out;
    int N, bx, by;
    if (blk < 4096) {
        in = w_attn; out = Wt1; N = N1;
        int t = blk - 1024;
        bx = t % 96; by = t / 96;
    } else {
        in = w_proj; out = Wt2; N = C_;
        int t = blk - 4096;
        bx = t % 32; by = t / 32;
    }
    int tx = threadIdx.x & 31;
    int ty = threadIdx.x >> 5;
    int n0 = bx * 32;
    int k0 = by * 32;
#pragma unroll
    for (int rr = 0; rr < 32; rr += 8)
        tile[ty + rr][tx] = in[(size_t)(k0 + ty + rr) * N + n0 + tx];
    __syncthreads();
#pragma unroll
    for (int rr = 0; rr < 32; rr += 8)
        out[(size_t)(n0 + ty + rr) * K_ + k0 + tx] = f2bf(tile[tx][ty + rr]);
}

// ==== GEMM K-loop v3: 512 thr / 8 waves, TRIPLE buffer, 1 barrier/step ====
// Stage-issue AFTER the barrier: a wave writes buf (t+2)%3 only once all waves
// passed barrier(t), i.e. finished compute(t-1) on that same buffer (their
// ds_reads were consumed by MFMA operand waits before the barrier). This
// removes the 2nd barrier + LGKM0 and keeps 2 tiles in flight (vmcnt(2),
// never drained until the tail). sched_barrier(0) pins gld16 after s_barrier.
// Granule XOR-swizzle (proven conflict-free) unchanged.
template <bool SWAP>
static __device__ __forceinline__ void gemm_loop8(
    const unsigned short* __restrict__ A, const unsigned short* __restrict__ Bt,
    unsigned short (*As)[128 * 32], unsigned short (*Bs)[128 * 32],
    int row0, int col0, int tid, f32x4 (&acc)[2][4])
{
    const int lane = tid & 63;
    const int wave = tid >> 6;             // 0..7
    const int g = lane >> 4, cl = lane & 15;
    const int wr = (wave & 3) * 32, wc = (wave >> 2) * 64;
    const int srow = tid >> 2;             // 0..127
    const int sgran = tid & 3;
#pragma unroll
    for (int m = 0; m < 2; ++m)
#pragma unroll
        for (int n = 0; n < 4; ++n)
            acc[m][n] = (f32x4){0.f, 0.f, 0.f, 0.f};
    const int lg = sgran ^ ((srow >> 1) & 3);
    auto stage = [&](int buf, int k0) {
        gld16(A + (size_t)(row0 + srow) * K_ + k0 + lg * 8,
              (char*)&As[buf][0] + wave * 1024);
        gld16(Bt + (size_t)(col0 + srow) * K_ + k0 + lg * 8,
              (char*)&Bs[buf][0] + wave * 1024);
    };
    stage(0, 0);
    stage(1, 32);
    for (int t = 0; t < K_ / 32; ++t) {
        const int k0 = t * 32;
        if (k0 + 32 < K_) { VMCNT(2); }   // retire tile t; tile t+1 stays in flight
        else              { VMCNT(0); }
        __builtin_amdgcn_s_barrier();
        __builtin_amdgcn_sched_barrier(0);  // pin: stage must not hoist above barrier
        if (t + 2 < K_ / 32) stage((t + 2) % 3, k0 + 64);
        const int buf = t % 3;
        bf16x8 af[2], bfv[4];
#pragma unroll
        for (int m = 0; m < 2; ++m) {
            int ra = wr + m * 16 + cl;
            af[m] = bload(&As[buf][ra * 32 + (g ^ ((ra >> 1) & 3)) * 8]);
        }
#pragma unroll
        for (int n = 0; n < 4; ++n) {
            int rb = wc + n * 16 + cl;
            bfv[n] = bload(&Bs[buf][rb * 32 + (g ^ ((rb >> 1) & 3)) * 8]);
        }
#pragma unroll
        for (int m = 0; m < 2; ++m)
#pragma unroll
            for (int n = 0; n < 4; ++n)
                acc[m][n] = SWAP
                    ? __builtin_amdgcn_mfma_f32_16x16x32_bf16(bfv[n], af[m], acc[m][n], 0, 0, 0)
                    : __builtin_amdgcn_mfma_f32_16x16x32_bf16(af[m], bfv[n], acc[m][n], 0, 0, 0);
    }
}

// ---------------- GEMM1: qkv = Xb @ Wt1^T + b (8 waves, 3 blocks/CU) ----------------
__global__ __launch_bounds__(512, 6)
void gemm_qkv_kernel(const unsigned short* __restrict__ A,   // [4096][1024] bf16
                     const unsigned short* __restrict__ Bt,  // [3072][1024] bf16
                     const float* __restrict__ bias,         // [3072]
                     unsigned short* __restrict__ Qo,        // [BH][T][D] (pre-scaled)
                     unsigned short* __restrict__ Ko,        // [BH][T][D]
                     unsigned short* __restrict__ Vt)        // [BH][D][T]
{
    __shared__ unsigned short As[3][128 * 32];
    __shared__ unsigned short Bs[3][128 * 32];
    const int lin = blockIdx.x + gridDim.x * blockIdx.y;  // 0..767
    const int xcd = lin & 7;
    const int idx = lin >> 3;                              // 0..95
    const int bx = (xcd >> 1) * 8 + (idx & 7);             // 0..31
    const int by = (xcd & 1) * 12 + (idx >> 3);            // 0..23
    const int row0 = bx * 128, col0 = by * 128;

    const int tid = threadIdx.x;
    const int lane = tid & 63;
    const int wave = tid >> 6;
    const int g = lane >> 4, cl = lane & 15;
    const int wr = (wave & 3) * 32, wc = (wave >> 2) * 64;

    f32x4 acc[2][4];
    gemm_loop8<false>(A, Bt, As, Bs, row0, col0, tid, acc);

    const float QSCALE = 0.125f * 1.44269504088896340736f;  // 1/sqrt(D) * log2(e)
#pragma unroll
    for (int m = 0; m < 2; ++m) {
        int i0 = row0 + wr + m * 16 + g * 4;
        int b = i0 >> 11, t0 = i0 & 2047;   // 4 consecutive t from t0 (same b)
#pragma unroll
        for (int n = 0; n < 4; ++n) {
            int j = col0 + wc + n * 16 + cl;
            int which = j >> 10;
            int c = j & 1023;
            int h = c >> 6, d = c & 63;
            float bv = bias[j];
            size_t bh = (size_t)(b * H_ + h);
            float v0 = acc[m][n][0] + bv;
            float v1 = acc[m][n][1] + bv;
            float v2 = acc[m][n][2] + bv;
            float v3 = acc[m][n][3] + bv;
            if (which == 2) {
                uint2_t w;
                w.x = packbf(v0, v1);
                w.y = packbf(v2, v3);
                *(uint2_t*)&Vt[(bh * D_ + d) * T_ + t0] = w;
            } else if (which == 0) {
                Qo[(bh * T_ + t0 + 0) * D_ + d] = f2bf_hw(v0 * QSCALE);
                Qo[(bh * T_ + t0 + 1) * D_ + d] = f2bf_hw(v1 * QSCALE);
                Qo[(bh * T_ + t0 + 2) * D_ + d] = f2bf_hw(v2 * QSCALE);
                Qo[(bh * T_ + t0 + 3) * D_ + d] = f2bf_hw(v3 * QSCALE);
            } else {
                Ko[(bh * T_ + t0 + 0) * D_ + d] = f2bf_hw(v0);
                Ko[(bh * T_ + t0 + 1) * D_ + d] = f2bf_hw(v1);
                Ko[(bh * T_ + t0 + 2) * D_ + d] = f2bf_hw(v2);
                Ko[(bh * T_ + t0 + 3) * D_ + d] = f2bf_hw(v3);
            }
        }
    }
}

// -------- GEMM2: out = AO @ Wt2^T + b (fp32 out, swapped -> f32x4 stores) --------
__global__ __launch_bounds__(512, 4)
void gemm_proj_kernel(const unsigned short* __restrict__ A,   // [4096][1024] bf16
                      const unsigned short* __restrict__ Bt,  // [1024][1024] bf16
                      const float* __restrict__ bias,         // [1024]
                      float* __restrict__ out)                // [4096][1024] f32
{
    __shared__ unsigned short As[3][128 * 32];
    __shared__ unsigned short Bs[3][128 * 32];
    const int row0 = blockIdx.x * 128, col0 = blockIdx.y * 128;
    const int tid = threadIdx.x;
    const int lane = tid & 63;
    const int wave = tid >> 6;
    const int g = lane >> 4, cl = lane & 15;
    const int wr = (wave & 3) * 32, wc = (wave >> 2) * 64;

    f32x4 acc[2][4];
    gemm_loop8<true>(A, Bt, As, Bs, row0, col0, tid, acc);

#pragma unroll
    for (int m = 0; m < 2; ++m) {
        int i = row0 + wr + m * 16 + cl;
#pragma unroll
        for (int n = 0; n < 4; ++n) {
            int j0 = col0 + wc + n * 16 + g * 4;
            float4 bv = *(const float4*)&bias[j0];
            f32x4 o = acc[m][n];
            o[0] += bv.x; o[1] += bv.y; o[2] += bv.z; o[3] += bv.w;
            *(f32x4*)&out[(size_t)i * C_ + j0] = o;
        }
    }
}

// ---------------- flash attention (R17 verbatim — proven ~49us) ----------------
__global__ __launch_bounds__(256)
void attn_kernel(const unsigned short* __restrict__ Q,   // [BH][T][D], pre-scaled
                 const unsigned short* __restrict__ Kb,  // [BH][T][D]
                 const unsigned short* __restrict__ Vh_, // [BH][D][T]
                 unsigned short* __restrict__ AO)        // [B][T][C] bf16
{
    __shared__ unsigned short Klds[2][64 * 64];   // 16 KB
    __shared__ unsigned short Vlds[2][64 * 64];   // 16 KB
    __shared__ unsigned short Plds[4][16 * 64];   // 8 KB, XOR-swizzled rows
    const int lin = blockIdx.x;                   // 0..1023
    const int idx = lin >> 3;                     // 0..127
    const int bh  = (lin & 7) + 8 * (idx & 3);    // 0..31, head pinned to one XCD
    const int qt  = 31 - (idx >> 2);              // long tiles first
    const int b = bh >> 4, h = bh & 15;
    const int tid = threadIdx.x;
    const int lane = tid & 63;
    const int wave = tid >> 6;
    const int g = lane >> 4, cl = lane & 15;

    const unsigned short* Qh = Q + (size_t)bh * T_ * D_;
    const unsigned short* Kh = Kb + (size_t)bh * T_ * D_;
    const unsigned short* Vh = Vh_ + (size_t)bh * D_ * T_;

    const int srow = tid >> 3;  // 0..31
    const int sg   = tid & 7;
    const int pswz = (cl & 7) << 4;

    auto stage = [&](int bufi, int kb) {
#pragma unroll
        for (int c = 0; c < 2; ++c) {
            int r = srow + c * 32;
            int lg = sg ^ (r & 7);
            gld16(Kh + (size_t)(kb + r) * D_ + lg * 8,
                  (char*)&Klds[bufi][0] + c * 4096 + wave * 1024);
            gld16(Vh + (size_t)r * T_ + kb + lg * 8,
                  (char*)&Vlds[bufi][0] + c * 4096 + wave * 1024);
        }
    };

    const int q0 = qt * 64 + wave * 16;
    const int tq = q0 + cl;

    bf16x8 qf[2];
#pragma unroll
    for (int c2 = 0; c2 < 2; ++c2)
        qf[c2] = bload(Qh + (size_t)(q0 + cl) * D_ + c2 * 32 + g * 8);

    f32x4 oacc[4];
#pragma unroll
    for (int n = 0; n < 4; ++n) oacc[n] = (f32x4){0.f, 0.f, 0.f, 0.f};
    float m_run = -INFINITY;
    float l_part = 0.f;

    const int nk = qt + 1;
    stage(0, 0);
    int buf = 0;
    for (int kt = 0; kt < nk; ++kt) {
        if (kt + 1 < nk) { stage(buf ^ 1, (kt + 1) * 64); VMCNT(4); }
        else             { VMCNT(0); }
        __builtin_amdgcn_s_barrier();

        const int kb = kt * 64;
        f32x4 sc[4];
        __builtin_amdgcn_s_setprio(1);
#pragma unroll
        for (int n = 0; n < 4; ++n) {
            sc[n] = (f32x4){0.f, 0.f, 0.f, 0.f};
#pragma unroll
            for (int c2 = 0; c2 < 2; ++c2) {
                int pg = (c2 * 4 + g) ^ (cl & 7);
                bf16x8 kf = bload(&Klds[buf][(n * 16 + cl) * 64 + pg * 8]);
                sc[n] = __builtin_amdgcn_mfma_f32_16x16x32_bf16(kf, qf[c2], sc[n], 0, 0, 0);
            }
        }
        __builtin_amdgcn_s_setprio(0);
        if (kt == qt) {
#pragma unroll
            for (int n = 0; n < 4; ++n) {
                int k4 = kb + n * 16 + g * 4;
#pragma unroll
                for (int r = 0; r < 4; ++r)
                    if (k4 + r > tq) sc[n][r] = -INFINITY;
            }
        }
        float mx[4];
#pragma unroll
        for (int n = 0; n < 4; ++n)
            mx[n] = fmaxf(fmaxf(sc[n][0], sc[n][1]), fmaxf(sc[n][2], sc[n][3]));
        float lm = fmaxf(fmaxf(mx[0], mx[1]), fmaxf(mx[2], mx[3]));
        if (!__all(lm <= m_run + 8.f)) {
            float vmax = lm;
            vmax = fmaxf(vmax, __shfl_xor(vmax, 16, 64));
            vmax = fmaxf(vmax, __shfl_xor(vmax, 32, 64));
            float mn = fmaxf(m_run, vmax);
            float alpha = fexp2(m_run - mn);
            l_part *= alpha;
#pragma unroll
            for (int n = 0; n < 4; ++n)
#pragma unroll
                for (int r = 0; r < 4; ++r) oacc[n][r] *= alpha;
            m_run = mn;
        }
        float p[4][4], psub[4];
#pragma unroll
        for (int n = 0; n < 4; ++n) {
#pragma unroll
            for (int r = 0; r < 4; ++r) p[n][r] = fexp2(sc[n][r] - m_run);
            psub[n] = (p[n][0] + p[n][1]) + (p[n][2] + p[n][3]);
        }
        l_part += (psub[0] + psub[1]) + (psub[2] + psub[3]);
#pragma unroll
        for (int n = 0; n < 4; ++n) {
            uint2_t w;
            w.x = packbf(p[n][0], p[n][1]);
            w.y = packbf(p[n][2], p[n][3]);
            *(uint2_t*)((char*)&Plds[wave][0] + ((cl * 128 + n * 32 + g * 8) ^ pswz)) = w;
        }
        bf16x8 pf[2];
#pragma unroll
        for (int kk = 0; kk < 2; ++kk)
            pf[kk] = bload((const unsigned short*)
                ((char*)&Plds[wave][0] + ((cl * 128 + kk * 64 + g * 16) ^ pswz)));
        __builtin_amdgcn_s_setprio(1);
#pragma unroll
        for (int n = 0; n < 4; ++n) {
#pragma unroll
            for (int kk = 0; kk < 2; ++kk) {
                int pg = (kk * 4 + g) ^ (cl & 7);
                bf16x8 vfr = bload(&Vlds[buf][(n * 16 + cl) * 64 + pg * 8]);
                oacc[n] = __builtin_amdgcn_mfma_f32_16x16x32_bf16(vfr, pf[kk], oacc[n], 0, 0, 0);
            }
        }
        __builtin_amdgcn_s_setprio(0);
        LGKM0;
        __builtin_amdgcn_s_barrier();
        buf ^= 1;
    }
    float lt = l_part;
    lt += __shfl_xor(lt, 16, 64);
    lt += __shfl_xor(lt, 32, 64);
    float inv = 1.f / lt;
#pragma unroll
    for (int n = 0; n < 4; ++n) {
        uint2_t w;
        w.x = packbf(oacc[n][0] * inv, oacc[n][1] * inv);
        w.y = packbf(oacc[n][2] * inv, oacc[n][3] * inv);
        *(uint2_t*)&AO[((size_t)b * T_ + tq) * C_ + h * D_ + n * 16 + g * 4] = w;
    }
}

extern "C" void kernel_launch(void* const* d_in, const int* in_sizes, int n_in,
                              void* d_out, int out_size, void* d_ws, size_t ws_size,
                              hipStream_t stream) {
    (void)in_sizes; (void)n_in; (void)out_size; (void)ws_size;
    const float* x      = (const float*)d_in[0];
    const float* w_attn = (const float*)d_in[1];
    const float* b_attn = (const float*)d_in[2];
    const float* w_proj = (const float*)d_in[3];
    const float* b_proj = (const float*)d_in[4];
    float* out = (float*)d_out;

    char* ws = (char*)d_ws;
    unsigned short* Xb  = (unsigned short*)(ws);
    unsigned short* Wt1 = (unsigned short*)(ws + ((size_t)8  << 20));
    unsigned short* Wt2 = (unsigned short*)(ws + ((size_t)14 << 20));
    unsigned short* Qb  = (unsigned short*)(ws + ((size_t)16 << 20));
    unsigned short* Kb  = (unsigned short*)(ws + ((size_t)24 << 20));
    unsigned short* Vt  = (unsigned short*)(ws + ((size_t)32 << 20));
    unsigned short* AO  = Xb;  // Xb dead after gemm_qkv

    prologue_kernel<<<5120, 256, 0, stream>>>(x, w_attn, w_proj, Xb, Wt1, Wt2);
    gemm_qkv_kernel<<<dim3(M1 / 128, N1 / 128), 512, 0, stream>>>(Xb, Wt1, b_attn, Qb, Kb, Vt);
    attn_kernel<<<1024, 256, 0, stream>>>(Qb, Kb, Vt, AO);
    gemm_proj_kernel<<<dim3(M1 / 128, C_ / 128), 512, 0, stream>>>(AO, Wt2, b_proj, out);
}

// Round 21
// 106.190 us; speedup vs baseline: 1.1181x; 1.0032x over previous
//
#include <hip/hip_runtime.h>
#include <hip/hip_bf16.h>

#define B_ 2
#define T_ 2048
#define C_ 1024
#define H_ 16
#define D_ 64
#define M1 4096
#define N1 3072
#define K_ 1024

typedef __attribute__((ext_vector_type(8))) __bf16 bf16x8;
typedef __attribute__((ext_vector_type(4))) float f32x4;
typedef __attribute__((ext_vector_type(8))) unsigned short ushort8_t;
typedef __attribute__((ext_vector_type(4))) unsigned short ushort4_t;
typedef __attribute__((ext_vector_type(2))) unsigned int uint2_t;

static __device__ __forceinline__ unsigned short f2bf(float f) {
    unsigned int u = __builtin_bit_cast(unsigned int, f);
    u += 0x7fffu + ((u >> 16) & 1u);
    return (unsigned short)(u >> 16);
}
static __device__ __forceinline__ unsigned short f2bf_hw(float f) {
    return __builtin_bit_cast(unsigned short, (__bf16)f);
}
static __device__ __forceinline__ unsigned int packbf(float lo, float hi) {
    return (unsigned int)f2bf_hw(lo) | ((unsigned int)f2bf_hw(hi) << 16);
}
static __device__ __forceinline__ bf16x8 bload(const unsigned short* p) {
    return __builtin_bit_cast(bf16x8, *(const ushort8_t*)p);
}

// fast exp2 -> v_exp_f32
#if defined(__has_builtin)
#if __has_builtin(__builtin_amdgcn_exp2f)
#define HAVE_EXP2_BUILTIN 1
#endif
#endif
static __device__ __forceinline__ float fexp2(float x) {
#ifdef HAVE_EXP2_BUILTIN
    return __builtin_amdgcn_exp2f(x);
#else
    float r; asm("v_exp_f32 %0, %1" : "=v"(r) : "v"(x)); return r;
#endif
}

// ---- async global->LDS (16B per lane; LDS dest wave-uniform base + lane*16) ----
typedef __attribute__((address_space(1))) const unsigned int gu32;
typedef __attribute__((address_space(3))) unsigned int lu32;
static __device__ __forceinline__ void gld16(const void* g, void* l) {
    __builtin_amdgcn_global_load_lds((gu32*)g, (lu32*)l, 16, 0, 0);
}

#define VMCNT(n) asm volatile("s_waitcnt vmcnt(" #n ")" ::: "memory")
#define LGKM0    asm volatile("s_waitcnt lgkmcnt(0)" ::: "memory")

// ============ fused prologue: cast x + transpose both weights ============
__global__ __launch_bounds__(256)
void prologue_kernel(const float* __restrict__ x,
                     const float* __restrict__ w_attn,
                     const float* __restrict__ w_proj,
                     unsigned short* __restrict__ Xb,
                     unsigned short* __restrict__ Wt1,
                     unsigned short* __restrict__ Wt2)
{
    __shared__ float tile[32][33];
    const int blk = blockIdx.x;
    if (blk < 1024) {
        int idx = blk * 256 + threadIdx.x;
        const int n4 = (M1 * K_) / 4;
        for (int i = idx; i < n4; i += 1024 * 256) {
            float4 v = ((const float4*)x)[i];
            ushort4_t o;
            o.x = f2bf(v.x); o.y = f2bf(v.y); o.z = f2bf(v.z); o.w = f2bf(v.w);
            ((ushort4_t*)Xb)[i] = o;
        }
        return;
    }
    const float* in;
    unsigned short* out;
    int N, bx, by;
    if (blk < 4096) {
        in = w_attn; out = Wt1; N = N1;
        int t = blk - 1024;
        bx = t % 96; by = t / 96;
    } else {
        in = w_proj; out = Wt2; N = C_;
        int t = blk - 4096;
        bx = t % 32; by = t / 32;
    }
    int tx = threadIdx.x & 31;
    int ty = threadIdx.x >> 5;
    int n0 = bx * 32;
    int k0 = by * 32;
#pragma unroll
    for (int rr = 0; rr < 32; rr += 8)
        tile[ty + rr][tx] = in[(size_t)(k0 + ty + rr) * N + n0 + tx];
    __syncthreads();
#pragma unroll
    for (int rr = 0; rr < 32; rr += 8)
        out[(size_t)(n0 + ty + rr) * K_ + k0 + tx] = f2bf(tile[tx][ty + rr]);
}

// ==== GEMM K-loop v3: 512 thr / 8 waves, TRIPLE buffer, 1 barrier/step ====
template <bool SWAP>
static __device__ __forceinline__ void gemm_loop8(
    const unsigned short* __restrict__ A, const unsigned short* __restrict__ Bt,
    unsigned short (*As)[128 * 32], unsigned short (*Bs)[128 * 32],
    int row0, int col0, int tid, f32x4 (&acc)[2][4])
{
    const int lane = tid & 63;
    const int wave = tid >> 6;             // 0..7
    const int g = lane >> 4, cl = lane & 15;
    const int wr = (wave & 3) * 32, wc = (wave >> 2) * 64;
    const int srow = tid >> 2;             // 0..127
    const int sgran = tid & 3;
#pragma unroll
    for (int m = 0; m < 2; ++m)
#pragma unroll
        for (int n = 0; n < 4; ++n)
            acc[m][n] = (f32x4){0.f, 0.f, 0.f, 0.f};
    const int lg = sgran ^ ((srow >> 1) & 3);
    auto stage = [&](int buf, int k0) {
        gld16(A + (size_t)(row0 + srow) * K_ + k0 + lg * 8,
              (char*)&As[buf][0] + wave * 1024);
        gld16(Bt + (size_t)(col0 + srow) * K_ + k0 + lg * 8,
              (char*)&Bs[buf][0] + wave * 1024);
    };
    stage(0, 0);
    stage(1, 32);
    for (int t = 0; t < K_ / 32; ++t) {
        const int k0 = t * 32;
        if (k0 + 32 < K_) { VMCNT(2); }
        else              { VMCNT(0); }
        __builtin_amdgcn_s_barrier();
        __builtin_amdgcn_sched_barrier(0);
        if (t + 2 < K_ / 32) stage((t + 2) % 3, k0 + 64);
        const int buf = t % 3;
        bf16x8 af[2], bfv[4];
#pragma unroll
        for (int m = 0; m < 2; ++m) {
            int ra = wr + m * 16 + cl;
            af[m] = bload(&As[buf][ra * 32 + (g ^ ((ra >> 1) & 3)) * 8]);
        }
#pragma unroll
        for (int n = 0; n < 4; ++n) {
            int rb = wc + n * 16 + cl;
            bfv[n] = bload(&Bs[buf][rb * 32 + (g ^ ((rb >> 1) & 3)) * 8]);
        }
#pragma unroll
        for (int m = 0; m < 2; ++m)
#pragma unroll
            for (int n = 0; n < 4; ++n)
                acc[m][n] = SWAP
                    ? __builtin_amdgcn_mfma_f32_16x16x32_bf16(bfv[n], af[m], acc[m][n], 0, 0, 0)
                    : __builtin_amdgcn_mfma_f32_16x16x32_bf16(af[m], bfv[n], acc[m][n], 0, 0, 0);
    }
}

// ---------------- GEMM1: qkv = Xb @ Wt1^T + b (8 waves, 3 blocks/CU) ----------------
__global__ __launch_bounds__(512, 6)
void gemm_qkv_kernel(const unsigned short* __restrict__ A,   // [4096][1024] bf16
                     const unsigned short* __restrict__ Bt,  // [3072][1024] bf16
                     const float* __restrict__ bias,         // [3072]
                     unsigned short* __restrict__ Qo,        // [BH][T][D] (pre-scaled)
                     unsigned short* __restrict__ Ko,        // [BH][T][D]
                     unsigned short* __restrict__ Vt)        // [BH][D][T]
{
    __shared__ unsigned short As[3][128 * 32];
    __shared__ unsigned short Bs[3][128 * 32];
    const int lin = blockIdx.x + gridDim.x * blockIdx.y;  // 0..767
    const int xcd = lin & 7;
    const int idx = lin >> 3;                              // 0..95
    const int bx = (xcd >> 1) * 8 + (idx & 7);             // 0..31
    const int by = (xcd & 1) * 12 + (idx >> 3);            // 0..23
    const int row0 = bx * 128, col0 = by * 128;

    const int tid = threadIdx.x;
    const int lane = tid & 63;
    const int wave = tid >> 6;
    const int g = lane >> 4, cl = lane & 15;
    const int wr = (wave & 3) * 32, wc = (wave >> 2) * 64;

    f32x4 acc[2][4];
    gemm_loop8<false>(A, Bt, As, Bs, row0, col0, tid, acc);

    const float QSCALE = 0.125f * 1.44269504088896340736f;  // 1/sqrt(D) * log2(e)
#pragma unroll
    for (int m = 0; m < 2; ++m) {
        int i0 = row0 + wr + m * 16 + g * 4;
        int b = i0 >> 11, t0 = i0 & 2047;   // 4 consecutive t from t0 (same b)
#pragma unroll
        for (int n = 0; n < 4; ++n) {
            int j = col0 + wc + n * 16 + cl;
            int which = j >> 10;
            int c = j & 1023;
            int h = c >> 6, d = c & 63;
            float bv = bias[j];
            size_t bh = (size_t)(b * H_ + h);
            float v0 = acc[m][n][0] + bv;
            float v1 = acc[m][n][1] + bv;
            float v2 = acc[m][n][2] + bv;
            float v3 = acc[m][n][3] + bv;
            if (which == 2) {
                uint2_t w;
                w.x = packbf(v0, v1);
                w.y = packbf(v2, v3);
                *(uint2_t*)&Vt[(bh * D_ + d) * T_ + t0] = w;
            } else if (which == 0) {
                Qo[(bh * T_ + t0 + 0) * D_ + d] = f2bf_hw(v0 * QSCALE);
                Qo[(bh * T_ + t0 + 1) * D_ + d] = f2bf_hw(v1 * QSCALE);
                Qo[(bh * T_ + t0 + 2) * D_ + d] = f2bf_hw(v2 * QSCALE);
                Qo[(bh * T_ + t0 + 3) * D_ + d] = f2bf_hw(v3 * QSCALE);
            } else {
                Ko[(bh * T_ + t0 + 0) * D_ + d] = f2bf_hw(v0);
                Ko[(bh * T_ + t0 + 1) * D_ + d] = f2bf_hw(v1);
                Ko[(bh * T_ + t0 + 2) * D_ + d] = f2bf_hw(v2);
                Ko[(bh * T_ + t0 + 3) * D_ + d] = f2bf_hw(v3);
            }
        }
    }
}

// -------- GEMM2: out = AO @ Wt2^T + b (fp32 out, swapped -> f32x4 stores) --------
__global__ __launch_bounds__(512, 4)
void gemm_proj_kernel(const unsigned short* __restrict__ A,   // [4096][1024] bf16
                      const unsigned short* __restrict__ Bt,  // [1024][1024] bf16
                      const float* __restrict__ bias,         // [1024]
                      float* __restrict__ out)                // [4096][1024] f32
{
    __shared__ unsigned short As[3][128 * 32];
    __shared__ unsigned short Bs[3][128 * 32];
    const int row0 = blockIdx.x * 128, col0 = blockIdx.y * 128;
    const int tid = threadIdx.x;
    const int lane = tid & 63;
    const int wave = tid >> 6;
    const int g = lane >> 4, cl = lane & 15;
    const int wr = (wave & 3) * 32, wc = (wave >> 2) * 64;

    f32x4 acc[2][4];
    gemm_loop8<true>(A, Bt, As, Bs, row0, col0, tid, acc);

#pragma unroll
    for (int m = 0; m < 2; ++m) {
        int i = row0 + wr + m * 16 + cl;
#pragma unroll
        for (int n = 0; n < 4; ++n) {
            int j0 = col0 + wc + n * 16 + g * 4;
            float4 bv = *(const float4*)&bias[j0];
            f32x4 o = acc[m][n];
            o[0] += bv.x; o[1] += bv.y; o[2] += bv.z; o[3] += bv.w;
            *(f32x4*)&out[(size_t)i * C_ + j0] = o;
        }
    }
}

// ---------------- flash attention (R17 body, single-barrier K-loop) ----------------
// grid 1024: xcd = lin&7; bh = xcd+8*(idx&3) (4 heads/XCD, L2-resident);
// qt = 31-(idx>>2) (long tiles first). LDS 40960 B = 4 blocks/CU.
// Single barrier/step: stage(t+1 into buf^1) AFTER barrier(t) — all waves
// passed barrier only after compute(t-1)'s ds_reads of buf^1 retired (lgkmcnt
// before MFMA use), so the overwrite is safe; trailing LGKM0+barrier deleted.
// VMCNT(0) at top retires stage(t) (the only outstanding vmem op).
__global__ __launch_bounds__(256)
void attn_kernel(const unsigned short* __restrict__ Q,   // [BH][T][D], pre-scaled
                 const unsigned short* __restrict__ Kb,  // [BH][T][D]
                 const unsigned short* __restrict__ Vh_, // [BH][D][T]
                 unsigned short* __restrict__ AO)        // [B][T][C] bf16
{
    __shared__ unsigned short Klds[2][64 * 64];   // 16 KB
    __shared__ unsigned short Vlds[2][64 * 64];   // 16 KB
    __shared__ unsigned short Plds[4][16 * 64];   // 8 KB, XOR-swizzled rows
    const int lin = blockIdx.x;                   // 0..1023
    const int idx = lin >> 3;                     // 0..127
    const int bh  = (lin & 7) + 8 * (idx & 3);    // 0..31, head pinned to one XCD
    const int qt  = 31 - (idx >> 2);              // long tiles first
    const int b = bh >> 4, h = bh & 15;
    const int tid = threadIdx.x;
    const int lane = tid & 63;
    const int wave = tid >> 6;
    const int g = lane >> 4, cl = lane & 15;

    const unsigned short* Qh = Q + (size_t)bh * T_ * D_;
    const unsigned short* Kh = Kb + (size_t)bh * T_ * D_;
    const unsigned short* Vh = Vh_ + (size_t)bh * D_ * T_;

    const int srow = tid >> 3;  // 0..31
    const int sg   = tid & 7;
    const int pswz = (cl & 7) << 4;

    auto stage = [&](int bufi, int kb) {
#pragma unroll
        for (int c = 0; c < 2; ++c) {
            int r = srow + c * 32;
            int lg = sg ^ (r & 7);
            gld16(Kh + (size_t)(kb + r) * D_ + lg * 8,
                  (char*)&Klds[bufi][0] + c * 4096 + wave * 1024);
            gld16(Vh + (size_t)r * T_ + kb + lg * 8,
                  (char*)&Vlds[bufi][0] + c * 4096 + wave * 1024);
        }
    };

    const int q0 = qt * 64 + wave * 16;
    const int tq = q0 + cl;

    bf16x8 qf[2];
#pragma unroll
    for (int c2 = 0; c2 < 2; ++c2)
        qf[c2] = bload(Qh + (size_t)(q0 + cl) * D_ + c2 * 32 + g * 8);

    f32x4 oacc[4];
#pragma unroll
    for (int n = 0; n < 4; ++n) oacc[n] = (f32x4){0.f, 0.f, 0.f, 0.f};
    float m_run = -INFINITY;
    float l_part = 0.f;

    const int nk = qt + 1;
    stage(0, 0);
    int buf = 0;
    for (int kt = 0; kt < nk; ++kt) {
        VMCNT(0);                       // retire stage(kt); nothing else in flight
        __builtin_amdgcn_s_barrier();
        __builtin_amdgcn_sched_barrier(0);  // pin: no memory op crosses the barrier
        if (kt + 1 < nk) stage(buf ^ 1, (kt + 1) * 64);

        const int kb = kt * 64;
        f32x4 sc[4];
        __builtin_amdgcn_s_setprio(1);
#pragma unroll
        for (int n = 0; n < 4; ++n) {
            sc[n] = (f32x4){0.f, 0.f, 0.f, 0.f};
#pragma unroll
            for (int c2 = 0; c2 < 2; ++c2) {
                int pg = (c2 * 4 + g) ^ (cl & 7);
                bf16x8 kf = bload(&Klds[buf][(n * 16 + cl) * 64 + pg * 8]);
                sc[n] = __builtin_amdgcn_mfma_f32_16x16x32_bf16(kf, qf[c2], sc[n], 0, 0, 0);
            }
        }
        __builtin_amdgcn_s_setprio(0);
        if (kt == qt) {
#pragma unroll
            for (int n = 0; n < 4; ++n) {
                int k4 = kb + n * 16 + g * 4;
#pragma unroll
                for (int r = 0; r < 4; ++r)
                    if (k4 + r > tq) sc[n][r] = -INFINITY;
            }
        }
        float mx[4];
#pragma unroll
        for (int n = 0; n < 4; ++n)
            mx[n] = fmaxf(fmaxf(sc[n][0], sc[n][1]), fmaxf(sc[n][2], sc[n][3]));
        float lm = fmaxf(fmaxf(mx[0], mx[1]), fmaxf(mx[2], mx[3]));
        if (!__all(lm <= m_run + 8.f)) {
            float vmax = lm;
            vmax = fmaxf(vmax, __shfl_xor(vmax, 16, 64));
            vmax = fmaxf(vmax, __shfl_xor(vmax, 32, 64));
            float mn = fmaxf(m_run, vmax);
            float alpha = fexp2(m_run - mn);
            l_part *= alpha;
#pragma unroll
            for (int n = 0; n < 4; ++n)
#pragma unroll
                for (int r = 0; r < 4; ++r) oacc[n][r] *= alpha;
            m_run = mn;
        }
        float p[4][4], psub[4];
#pragma unroll
        for (int n = 0; n < 4; ++n) {
#pragma unroll
            for (int r = 0; r < 4; ++r) p[n][r] = fexp2(sc[n][r] - m_run);
            psub[n] = (p[n][0] + p[n][1]) + (p[n][2] + p[n][3]);
        }
        l_part += (psub[0] + psub[1]) + (psub[2] + psub[3]);
#pragma unroll
        for (int n = 0; n < 4; ++n) {
            uint2_t w;
            w.x = packbf(p[n][0], p[n][1]);
            w.y = packbf(p[n][2], p[n][3]);
            *(uint2_t*)((char*)&Plds[wave][0] + ((cl * 128 + n * 32 + g * 8) ^ pswz)) = w;
        }
        bf16x8 pf[2];
#pragma unroll
        for (int kk = 0; kk < 2; ++kk)
            pf[kk] = bload((const unsigned short*)
                ((char*)&Plds[wave][0] + ((cl * 128 + kk * 64 + g * 16) ^ pswz)));
        __builtin_amdgcn_s_setprio(1);
#pragma unroll
        for (int n = 0; n < 4; ++n) {
#pragma unroll
            for (int kk = 0; kk < 2; ++kk) {
                int pg = (kk * 4 + g) ^ (cl & 7);
                bf16x8 vfr = bload(&Vlds[buf][(n * 16 + cl) * 64 + pg * 8]);
                oacc[n] = __builtin_amdgcn_mfma_f32_16x16x32_bf16(vfr, pf[kk], oacc[n], 0, 0, 0);
            }
        }
        __builtin_amdgcn_s_setprio(0);
        buf ^= 1;
    }
    float lt = l_part;
    lt += __shfl_xor(lt, 16, 64);
    lt += __shfl_xor(lt, 32, 64);
    float inv = 1.f / lt;
#pragma unroll
    for (int n = 0; n < 4; ++n) {
        uint2_t w;
        w.x = packbf(oacc[n][0] * inv, oacc[n][1] * inv);
        w.y = packbf(oacc[n][2] * inv, oacc[n][3] * inv);
        *(uint2_t*)&AO[((size_t)b * T_ + tq) * C_ + h * D_ + n * 16 + g * 4] = w;
    }
}

extern "C" void kernel_launch(void* const* d_in, const int* in_sizes, int n_in,
                              void* d_out, int out_size, void* d_ws, size_t ws_size,
                              hipStream_t stream) {
    (void)in_sizes; (void)n_in; (void)out_size; (void)ws_size;
    const float* x      = (const float*)d_in[0];
    const float* w_attn = (const float*)d_in[1];
    const float* b_attn = (const float*)d_in[2];
    const float* w_proj = (const float*)d_in[3];
    const float* b_proj = (const float*)d_in[4];
    float* out = (float*)d_out;

    char* ws = (char*)d_ws;
    unsigned short* Xb  = (unsigned short*)(ws);
    unsigned short* Wt1 = (unsigned short*)(ws + ((size_t)8  << 20));
    unsigned short* Wt2 = (unsigned short*)(ws + ((size_t)14 << 20));
    unsigned short* Qb  = (unsigned short*)(ws + ((size_t)16 << 20));
    unsigned short* Kb  = (unsigned short*)(ws + ((size_t)24 << 20));
    unsigned short* Vt  = (unsigned short*)(ws + ((size_t)32 << 20));
    unsigned short* AO  = Xb;  // Xb dead after gemm_qkv

    prologue_kernel<<<5120, 256, 0, stream>>>(x, w_attn, w_proj, Xb, Wt1, Wt2);
    gemm_qkv_kernel<<<dim3(M1 / 128, N1 / 128), 512, 0, stream>>>(Xb, Wt1, b_attn, Qb, Kb, Vt);
    attn_kernel<<<1024, 256, 0, stream>>>(Qb, Kb, Vt, AO);
    gemm_proj_kernel<<<dim3(M1 / 128, C_ / 128), 512, 0, stream>>>(AO, Wt2, b_proj, out);
}

// Round 22
// 104.031 us; speedup vs baseline: 1.1413x; 1.0208x over previous
//
#include <hip/hip_runtime.h>
#include <hip/hip_bf16.h>

#define B_ 2
#define T_ 2048
#define C_ 1024
#define H_ 16
#define D_ 64
#define M1 4096
#define N1 3072
#define K_ 1024

typedef __attribute__((ext_vector_type(8))) __bf16 bf16x8;
typedef __attribute__((ext_vector_type(4))) float f32x4;
typedef __attribute__((ext_vector_type(8))) unsigned short ushort8_t;
typedef __attribute__((ext_vector_type(4))) unsigned short ushort4_t;
typedef __attribute__((ext_vector_type(2))) unsigned int uint2_t;

static __device__ __forceinline__ unsigned short f2bf(float f) {
    unsigned int u = __builtin_bit_cast(unsigned int, f);
    u += 0x7fffu + ((u >> 16) & 1u);
    return (unsigned short)(u >> 16);
}
static __device__ __forceinline__ unsigned short f2bf_hw(float f) {
    return __builtin_bit_cast(unsigned short, (__bf16)f);
}
static __device__ __forceinline__ unsigned int packbf(float lo, float hi) {
    return (unsigned int)f2bf_hw(lo) | ((unsigned int)f2bf_hw(hi) << 16);
}
static __device__ __forceinline__ bf16x8 bload(const unsigned short* p) {
    return __builtin_bit_cast(bf16x8, *(const ushort8_t*)p);
}

// fast exp2 -> v_exp_f32
#if defined(__has_builtin)
#if __has_builtin(__builtin_amdgcn_exp2f)
#define HAVE_EXP2_BUILTIN 1
#endif
#endif
static __device__ __forceinline__ float fexp2(float x) {
#ifdef HAVE_EXP2_BUILTIN
    return __builtin_amdgcn_exp2f(x);
#else
    float r; asm("v_exp_f32 %0, %1" : "=v"(r) : "v"(x)); return r;
#endif
}

// ---- async global->LDS (16B per lane; LDS dest wave-uniform base + lane*16) ----
typedef __attribute__((address_space(1))) const unsigned int gu32;
typedef __attribute__((address_space(3))) unsigned int lu32;
static __device__ __forceinline__ void gld16(const void* g, void* l) {
    __builtin_amdgcn_global_load_lds((gu32*)g, (lu32*)l, 16, 0, 0);
}

#define VMCNT(n) asm volatile("s_waitcnt vmcnt(" #n ")" ::: "memory")
#define LGKM0    asm volatile("s_waitcnt lgkmcnt(0)" ::: "memory")

// ============ fused prologue: cast x + transpose both weights ============
__global__ __launch_bounds__(256)
void prologue_kernel(const float* __restrict__ x,
                     const float* __restrict__ w_attn,
                     const float* __restrict__ w_proj,
                     unsigned short* __restrict__ Xb,
                     unsigned short* __restrict__ Wt1,
                     unsigned short* __restrict__ Wt2)
{
    __shared__ float tile[32][33];
    const int blk = blockIdx.x;
    if (blk < 1024) {
        int idx = blk * 256 + threadIdx.x;
        const int n4 = (M1 * K_) / 4;
        for (int i = idx; i < n4; i += 1024 * 256) {
            float4 v = ((const float4*)x)[i];
            ushort4_t o;
            o.x = f2bf(v.x); o.y = f2bf(v.y); o.z = f2bf(v.z); o.w = f2bf(v.w);
            ((ushort4_t*)Xb)[i] = o;
        }
        return;
    }
    const float* in;
    unsigned short* out;
    int N, bx, by;
    if (blk < 4096) {
        in = w_attn; out = Wt1; N = N1;
        int t = blk - 1024;
        bx = t % 96; by = t / 96;
    } else {
        in = w_proj; out = Wt2; N = C_;
        int t = blk - 4096;
        bx = t % 32; by = t / 32;
    }
    int tx = threadIdx.x & 31;
    int ty = threadIdx.x >> 5;
    int n0 = bx * 32;
    int k0 = by * 32;
#pragma unroll
    for (int rr = 0; rr < 32; rr += 8)
        tile[ty + rr][tx] = in[(size_t)(k0 + ty + rr) * N + n0 + tx];
    __syncthreads();
#pragma unroll
    for (int rr = 0; rr < 32; rr += 8)
        out[(size_t)(n0 + ty + rr) * K_ + k0 + tx] = f2bf(tile[tx][ty + rr]);
}

// ==== GEMM K-loop v3: 512 thr / 8 waves, TRIPLE buffer, 1 barrier/step ====
template <bool SWAP>
static __device__ __forceinline__ void gemm_loop8(
    const unsigned short* __restrict__ A, const unsigned short* __restrict__ Bt,
    unsigned short (*As)[128 * 32], unsigned short (*Bs)[128 * 32],
    int row0, int col0, int tid, f32x4 (&acc)[2][4])
{
    const int lane = tid & 63;
    const int wave = tid >> 6;             // 0..7
    const int g = lane >> 4, cl = lane & 15;
    const int wr = (wave & 3) * 32, wc = (wave >> 2) * 64;
    const int srow = tid >> 2;             // 0..127
    const int sgran = tid & 3;
#pragma unroll
    for (int m = 0; m < 2; ++m)
#pragma unroll
        for (int n = 0; n < 4; ++n)
            acc[m][n] = (f32x4){0.f, 0.f, 0.f, 0.f};
    const int lg = sgran ^ ((srow >> 1) & 3);
    auto stage = [&](int buf, int k0) {
        gld16(A + (size_t)(row0 + srow) * K_ + k0 + lg * 8,
              (char*)&As[buf][0] + wave * 1024);
        gld16(Bt + (size_t)(col0 + srow) * K_ + k0 + lg * 8,
              (char*)&Bs[buf][0] + wave * 1024);
    };
    stage(0, 0);
    stage(1, 32);
    for (int t = 0; t < K_ / 32; ++t) {
        const int k0 = t * 32;
        if (k0 + 32 < K_) { VMCNT(2); }
        else              { VMCNT(0); }
        __builtin_amdgcn_s_barrier();
        __builtin_amdgcn_sched_barrier(0);
        if (t + 2 < K_ / 32) stage((t + 2) % 3, k0 + 64);
        const int buf = t % 3;
        bf16x8 af[2], bfv[4];
#pragma unroll
        for (int m = 0; m < 2; ++m) {
            int ra = wr + m * 16 + cl;
            af[m] = bload(&As[buf][ra * 32 + (g ^ ((ra >> 1) & 3)) * 8]);
        }
#pragma unroll
        for (int n = 0; n < 4; ++n) {
            int rb = wc + n * 16 + cl;
            bfv[n] = bload(&Bs[buf][rb * 32 + (g ^ ((rb >> 1) & 3)) * 8]);
        }
#pragma unroll
        for (int m = 0; m < 2; ++m)
#pragma unroll
            for (int n = 0; n < 4; ++n)
                acc[m][n] = SWAP
                    ? __builtin_amdgcn_mfma_f32_16x16x32_bf16(bfv[n], af[m], acc[m][n], 0, 0, 0)
                    : __builtin_amdgcn_mfma_f32_16x16x32_bf16(af[m], bfv[n], acc[m][n], 0, 0, 0);
    }
}

// ---------------- GEMM1: qkv = Xb @ Wt1^T + b (8 waves, 3 blocks/CU) ----------------
__global__ __launch_bounds__(512, 6)
void gemm_qkv_kernel(const unsigned short* __restrict__ A,   // [4096][1024] bf16
                     const unsigned short* __restrict__ Bt,  // [3072][1024] bf16
                     const float* __restrict__ bias,         // [3072]
                     unsigned short* __restrict__ Qo,        // [BH][T][D] (pre-scaled)
                     unsigned short* __restrict__ Ko,        // [BH][T][D]
                     unsigned short* __restrict__ Vt)        // [BH][D][T]
{
    __shared__ unsigned short As[3][128 * 32];
    __shared__ unsigned short Bs[3][128 * 32];
    const int lin = blockIdx.x + gridDim.x * blockIdx.y;  // 0..767
    const int xcd = lin & 7;
    const int idx = lin >> 3;                              // 0..95
    const int bx = (xcd >> 1) * 8 + (idx & 7);             // 0..31
    const int by = (xcd & 1) * 12 + (idx >> 3);            // 0..23
    const int row0 = bx * 128, col0 = by * 128;

    const int tid = threadIdx.x;
    const int lane = tid & 63;
    const int wave = tid >> 6;
    const int g = lane >> 4, cl = lane & 15;
    const int wr = (wave & 3) * 32, wc = (wave >> 2) * 64;

    f32x4 acc[2][4];
    gemm_loop8<false>(A, Bt, As, Bs, row0, col0, tid, acc);

    const float QSCALE = 0.125f * 1.44269504088896340736f;  // 1/sqrt(D) * log2(e)
#pragma unroll
    for (int m = 0; m < 2; ++m) {
        int i0 = row0 + wr + m * 16 + g * 4;
        int b = i0 >> 11, t0 = i0 & 2047;   // 4 consecutive t from t0 (same b)
#pragma unroll
        for (int n = 0; n < 4; ++n) {
            int j = col0 + wc + n * 16 + cl;
            int which = j >> 10;
            int c = j & 1023;
            int h = c >> 6, d = c & 63;
            float bv = bias[j];
            size_t bh = (size_t)(b * H_ + h);
            float v0 = acc[m][n][0] + bv;
            float v1 = acc[m][n][1] + bv;
            float v2 = acc[m][n][2] + bv;
            float v3 = acc[m][n][3] + bv;
            if (which == 2) {
                uint2_t w;
                w.x = packbf(v0, v1);
                w.y = packbf(v2, v3);
                *(uint2_t*)&Vt[(bh * D_ + d) * T_ + t0] = w;
            } else if (which == 0) {
                Qo[(bh * T_ + t0 + 0) * D_ + d] = f2bf_hw(v0 * QSCALE);
                Qo[(bh * T_ + t0 + 1) * D_ + d] = f2bf_hw(v1 * QSCALE);
                Qo[(bh * T_ + t0 + 2) * D_ + d] = f2bf_hw(v2 * QSCALE);
                Qo[(bh * T_ + t0 + 3) * D_ + d] = f2bf_hw(v3 * QSCALE);
            } else {
                Ko[(bh * T_ + t0 + 0) * D_ + d] = f2bf_hw(v0);
                Ko[(bh * T_ + t0 + 1) * D_ + d] = f2bf_hw(v1);
                Ko[(bh * T_ + t0 + 2) * D_ + d] = f2bf_hw(v2);
                Ko[(bh * T_ + t0 + 3) * D_ + d] = f2bf_hw(v3);
            }
        }
    }
}

// -------- GEMM2: out = AO @ Wt2^T + b (fp32 out, swapped -> f32x4 stores) --------
__global__ __launch_bounds__(512, 4)
void gemm_proj_kernel(const unsigned short* __restrict__ A,   // [4096][1024] bf16
                      const unsigned short* __restrict__ Bt,  // [1024][1024] bf16
                      const float* __restrict__ bias,         // [1024]
                      float* __restrict__ out)                // [4096][1024] f32
{
    __shared__ unsigned short As[3][128 * 32];
    __shared__ unsigned short Bs[3][128 * 32];
    const int row0 = blockIdx.x * 128, col0 = blockIdx.y * 128;
    const int tid = threadIdx.x;
    const int lane = tid & 63;
    const int wave = tid >> 6;
    const int g = lane >> 4, cl = lane & 15;
    const int wr = (wave & 3) * 32, wc = (wave >> 2) * 64;

    f32x4 acc[2][4];
    gemm_loop8<true>(A, Bt, As, Bs, row0, col0, tid, acc);

#pragma unroll
    for (int m = 0; m < 2; ++m) {
        int i = row0 + wr + m * 16 + cl;
#pragma unroll
        for (int n = 0; n < 4; ++n) {
            int j0 = col0 + wc + n * 16 + g * 4;
            float4 bv = *(const float4*)&bias[j0];
            f32x4 o = acc[m][n];
            o[0] += bv.x; o[1] += bv.y; o[2] += bv.z; o[3] += bv.w;
            *(f32x4*)&out[(size_t)i * C_ + j0] = o;
        }
    }
}

// ---------------- flash attention (single-barrier, diagonal peeled) ----------------
// grid 1024: xcd = lin&7; bh = xcd+8*(idx&3) (4 heads/XCD, L2-resident);
// qt = 31-(idx>>2) (long tiles first). LDS 40960 B = 4 blocks/CU.
// Main loop (kt=0..qt-1): no mask code, unconditional next-tile staging.
// Diagonal step peeled. max3-shaped reductions (v_max3_f32 fusable).
__global__ __launch_bounds__(256)
void attn_kernel(const unsigned short* __restrict__ Q,   // [BH][T][D], pre-scaled
                 const unsigned short* __restrict__ Kb,  // [BH][T][D]
                 const unsigned short* __restrict__ Vh_, // [BH][D][T]
                 unsigned short* __restrict__ AO)        // [B][T][C] bf16
{
    __shared__ unsigned short Klds[2][64 * 64];   // 16 KB
    __shared__ unsigned short Vlds[2][64 * 64];   // 16 KB
    __shared__ unsigned short Plds[4][16 * 64];   // 8 KB, XOR-swizzled rows
    const int lin = blockIdx.x;                   // 0..1023
    const int idx = lin >> 3;                     // 0..127
    const int bh  = (lin & 7) + 8 * (idx & 3);    // 0..31, head pinned to one XCD
    const int qt  = 31 - (idx >> 2);              // long tiles first
    const int b = bh >> 4, h = bh & 15;
    const int tid = threadIdx.x;
    const int lane = tid & 63;
    const int wave = tid >> 6;
    const int g = lane >> 4, cl = lane & 15;

    const unsigned short* Qh = Q + (size_t)bh * T_ * D_;
    const unsigned short* Kh = Kb + (size_t)bh * T_ * D_;
    const unsigned short* Vh = Vh_ + (size_t)bh * D_ * T_;

    const int srow = tid >> 3;  // 0..31
    const int sg   = tid & 7;
    const int pswz = (cl & 7) << 4;

    auto stage = [&](int bufi, int kb) {
#pragma unroll
        for (int c = 0; c < 2; ++c) {
            int r = srow + c * 32;
            int lg = sg ^ (r & 7);
            gld16(Kh + (size_t)(kb + r) * D_ + lg * 8,
                  (char*)&Klds[bufi][0] + c * 4096 + wave * 1024);
            gld16(Vh + (size_t)r * T_ + kb + lg * 8,
                  (char*)&Vlds[bufi][0] + c * 4096 + wave * 1024);
        }
    };

    const int q0 = qt * 64 + wave * 16;
    const int tq = q0 + cl;

    bf16x8 qf[2];
#pragma unroll
    for (int c2 = 0; c2 < 2; ++c2)
        qf[c2] = bload(Qh + (size_t)(q0 + cl) * D_ + c2 * 32 + g * 8);

    f32x4 oacc[4];
#pragma unroll
    for (int n = 0; n < 4; ++n) oacc[n] = (f32x4){0.f, 0.f, 0.f, 0.f};
    float m_run = -INFINITY;
    float l_part = 0.f;

    // one kt-step (after barrier, staging already issued by caller)
    auto attn_step = [&](int kb, int buf, bool diag) {
        f32x4 sc[4];
        __builtin_amdgcn_s_setprio(1);
#pragma unroll
        for (int n = 0; n < 4; ++n) {
            sc[n] = (f32x4){0.f, 0.f, 0.f, 0.f};
#pragma unroll
            for (int c2 = 0; c2 < 2; ++c2) {
                int pg = (c2 * 4 + g) ^ (cl & 7);
                bf16x8 kf = bload(&Klds[buf][(n * 16 + cl) * 64 + pg * 8]);
                sc[n] = __builtin_amdgcn_mfma_f32_16x16x32_bf16(kf, qf[c2], sc[n], 0, 0, 0);
            }
        }
        __builtin_amdgcn_s_setprio(0);
        if (diag) {
#pragma unroll
            for (int n = 0; n < 4; ++n) {
                int k4 = kb + n * 16 + g * 4;
#pragma unroll
                for (int r = 0; r < 4; ++r)
                    if (k4 + r > tq) sc[n][r] = -INFINITY;
            }
        }
        // max over 16 values, max3-shaped (v_max3_f32): 8 ops, depth 3
        float t0 = fmaxf(fmaxf(sc[0][0], sc[0][1]), sc[0][2]);
        float t1 = fmaxf(fmaxf(sc[0][3], sc[1][0]), sc[1][1]);
        float t2 = fmaxf(fmaxf(sc[1][2], sc[1][3]), sc[2][0]);
        float t3 = fmaxf(fmaxf(sc[2][1], sc[2][2]), sc[2][3]);
        float t4 = fmaxf(fmaxf(sc[3][0], sc[3][1]), sc[3][2]);
        float u0 = fmaxf(fmaxf(t0, t1), t2);
        float u1 = fmaxf(fmaxf(t3, t4), sc[3][3]);
        float lm = fmaxf(u0, u1);
        if (!__all(lm <= m_run + 8.f)) {
            float vmax = lm;
            vmax = fmaxf(vmax, __shfl_xor(vmax, 16, 64));
            vmax = fmaxf(vmax, __shfl_xor(vmax, 32, 64));
            float mn = fmaxf(m_run, vmax);
            float alpha = fexp2(m_run - mn);
            l_part *= alpha;
#pragma unroll
            for (int n = 0; n < 4; ++n)
#pragma unroll
                for (int r = 0; r < 4; ++r) oacc[n][r] *= alpha;
            m_run = mn;
        }
        float p[4][4], psub[4];
#pragma unroll
        for (int n = 0; n < 4; ++n) {
#pragma unroll
            for (int r = 0; r < 4; ++r) p[n][r] = fexp2(sc[n][r] - m_run);
            psub[n] = (p[n][0] + p[n][1]) + (p[n][2] + p[n][3]);
        }
        l_part += (psub[0] + psub[1]) + (psub[2] + psub[3]);
#pragma unroll
        for (int n = 0; n < 4; ++n) {
            uint2_t w;
            w.x = packbf(p[n][0], p[n][1]);
            w.y = packbf(p[n][2], p[n][3]);
            *(uint2_t*)((char*)&Plds[wave][0] + ((cl * 128 + n * 32 + g * 8) ^ pswz)) = w;
        }
        bf16x8 pf[2];
#pragma unroll
        for (int kk = 0; kk < 2; ++kk)
            pf[kk] = bload((const unsigned short*)
                ((char*)&Plds[wave][0] + ((cl * 128 + kk * 64 + g * 16) ^ pswz)));
        __builtin_amdgcn_s_setprio(1);
#pragma unroll
        for (int n = 0; n < 4; ++n) {
#pragma unroll
            for (int kk = 0; kk < 2; ++kk) {
                int pg = (kk * 4 + g) ^ (cl & 7);
                bf16x8 vfr = bload(&Vlds[buf][(n * 16 + cl) * 64 + pg * 8]);
                oacc[n] = __builtin_amdgcn_mfma_f32_16x16x32_bf16(vfr, pf[kk], oacc[n], 0, 0, 0);
            }
        }
        __builtin_amdgcn_s_setprio(0);
    };

    stage(0, 0);
    int buf = 0;
    // ---- main loop: kt = 0..qt-1, unmasked, unconditional staging ----
    for (int kt = 0; kt < qt; ++kt) {
        VMCNT(0);
        __builtin_amdgcn_s_barrier();
        __builtin_amdgcn_sched_barrier(0);
        stage(buf ^ 1, (kt + 1) * 64);
        attn_step(kt * 64, buf, false);
        buf ^= 1;
    }
    // ---- peeled diagonal step ----
    VMCNT(0);
    __builtin_amdgcn_s_barrier();
    __builtin_amdgcn_sched_barrier(0);
    attn_step(qt * 64, buf, true);

    float lt = l_part;
    lt += __shfl_xor(lt, 16, 64);
    lt += __shfl_xor(lt, 32, 64);
    float inv = 1.f / lt;
#pragma unroll
    for (int n = 0; n < 4; ++n) {
        uint2_t w;
        w.x = packbf(oacc[n][0] * inv, oacc[n][1] * inv);
        w.y = packbf(oacc[n][2] * inv, oacc[n][3] * inv);
        *(uint2_t*)&AO[((size_t)b * T_ + tq) * C_ + h * D_ + n * 16 + g * 4] = w;
    }
}

extern "C" void kernel_launch(void* const* d_in, const int* in_sizes, int n_in,
                              void* d_out, int out_size, void* d_ws, size_t ws_size,
                              hipStream_t stream) {
    (void)in_sizes; (void)n_in; (void)out_size; (void)ws_size;
    const float* x      = (const float*)d_in[0];
    const float* w_attn = (const float*)d_in[1];
    const float* b_attn = (const float*)d_in[2];
    const float* w_proj = (const float*)d_in[3];
    const float* b_proj = (const float*)d_in[4];
    float* out = (float*)d_out;

    char* ws = (char*)d_ws;
    unsigned short* Xb  = (unsigned short*)(ws);
    unsigned short* Wt1 = (unsigned short*)(ws + ((size_t)8  << 20));
    unsigned short* Wt2 = (unsigned short*)(ws + ((size_t)14 << 20));
    unsigned short* Qb  = (unsigned short*)(ws + ((size_t)16 << 20));
    unsigned short* Kb  = (unsigned short*)(ws + ((size_t)24 << 20));
    unsigned short* Vt  = (unsigned short*)(ws + ((size_t)32 << 20));
    unsigned short* AO  = Xb;  // Xb dead after gemm_qkv

    prologue_kernel<<<5120, 256, 0, stream>>>(x, w_attn, w_proj, Xb, Wt1, Wt2);
    gemm_qkv_kernel<<<dim3(M1 / 128, N1 / 128), 512, 0, stream>>>(Xb, Wt1, b_attn, Qb, Kb, Vt);
    attn_kernel<<<1024, 256, 0, stream>>>(Qb, Kb, Vt, AO);
    gemm_proj_kernel<<<dim3(M1 / 128, C_ / 128), 512, 0, stream>>>(AO, Wt2, b_proj, out);
}